// Round 10
// baseline (277.588 us; speedup 1.0000x reference)
//
#include <hip/hip_runtime.h>
#include <cstdint>

#define N_NODES 50000
#define N_EDGES 1600000
#define NH 4
#define CC 32
#define HC 128          // NH*CC
#define LAT 32
#define NEG_SLOPE 0.2f

// fused k_pre role split: [count | node | v | w1t | w2t]
#define NB_CNT  250                      // 250 x 6400-edge chunks
#define CH_E    6400
#define NB_NODE 25                       // node: 2048 nodes per block
#define NB_PRE  (NB_CNT + NB_NODE + 3)   // +v +w1t +w2t

// bucketed scatter: bucket = dst >> 8 (256 nodes / bucket)
#define NBUCK 196                        // ceil(50000/256)
#define P1_T  512
#define P1_EPB (P1_T * 4)                // 2048 edges per phase-1 block
#define P1_BLOCKS ((N_EDGES + P1_EPB - 1) / P1_EPB)   // 782
#define CAP  8960                        // LDS bucket capacity (mean 8192 + 8.5 sigma)

typedef uint32_t u32x4 __attribute__((ext_vector_type(4)));
typedef __bf16   bf16x8 __attribute__((ext_vector_type(8)));
typedef float    f32x4 __attribute__((ext_vector_type(4)));

// ---------------- bf16 helpers (RNE pack, shift-unpack) ----------------
__device__ __forceinline__ float bflo(uint32_t u) {
    union { uint32_t i; float f; } c; c.i = u << 16; return c.f;
}
__device__ __forceinline__ float bfhi(uint32_t u) {
    union { uint32_t i; float f; } c; c.i = u & 0xFFFF0000u; return c.f;
}
__device__ __forceinline__ uint32_t f2bf(float f) {
    union { float f; uint32_t i; } c; c.f = f;
    return (c.i + 0x7FFFu + ((c.i >> 16) & 1u)) >> 16;
}
__device__ __forceinline__ uint32_t pack2(float a, float b) {
    return f2bf(a) | (f2bf(b) << 16);
}
__device__ __forceinline__ float bpermf(int byteIdx, float v) {
    return __int_as_float(__builtin_amdgcn_ds_bpermute(byteIdx, __float_as_int(v)));
}
// fp8 e4m3fn pack/unpack (ae only feeds the self-loop mean -> 6% rel err ok)
__device__ __forceinline__ uint32_t f2e4m3(float x) {
    uint32_t u = __float_as_uint(x);
    uint32_t s = u >> 31;
    uint32_t mag = u & 0x7fffffffu;
    mag += 0x7ffffu + ((mag >> 20) & 1u);       // RNE at bit 20
    uint32_t e = mag >> 23;
    if (e < 121u) return s << 7;                // underflow -> 0
    uint32_t code = ((e - 120u) << 3) | ((mag >> 20) & 7u);
    if (code > 0x7Eu) code = 0x7Eu;             // clamp to 448
    return (s << 7) | code;
}
__device__ __forceinline__ float e4m32f(uint32_t b) {
    uint32_t e = (b >> 3) & 15u;
    if (e == 0u) return 0.f;
    return __uint_as_float(((b >> 7) << 31) | ((e + 120u) << 23) | ((b & 7u) << 20));
}

// ---------------------------------------------------------------- kernels

// zero the degree counters (kernel, not memset: graph-capture-safe and gives
// the cross-kernel ordering the atomic-count role needs)
__global__ __launch_bounds__(1024) void k_zero(int* __restrict__ cnt) {
    int i = blockIdx.x * 1024 + threadIdx.x;
    if (i < N_NODES) cnt[i] = 0;
}

// fused front end: [count | node | v | w1t | w2t] by blockIdx range.
// hist+reduce machinery replaced by direct global atomicAdd on cnt
// (1.6M atomics over 50000 L2-resident counters, ~32 hits each) —
// saves the 25MB hist write + 25MB hist read.
__global__ __launch_bounds__(256) void k_pre(const float* __restrict__ x,
                                             const int* __restrict__ ei,
                                             const float* __restrict__ W_gat,
                                             const float* __restrict__ att_src,
                                             const float* __restrict__ att_dst,
                                             const float* __restrict__ W_edge,
                                             const float* __restrict__ att_edge,
                                             const float* __restrict__ W1,
                                             const float* __restrict__ W2,
                                             int* __restrict__ cnt,
                                             float4* __restrict__ a_src,
                                             float4* __restrict__ a_dst,
                                             float* __restrict__ v,
                                             uint16_t* __restrict__ W1T_hi,
                                             uint16_t* __restrict__ W1T_lo,
                                             uint16_t* __restrict__ W2T_hi,
                                             uint16_t* __restrict__ W2T_lo) {
    int bid = blockIdx.x, t = threadIdx.x;
    if (bid < NB_CNT) {
        int base = bid * CH_E;
        #pragma unroll 1
        for (int it = 0; it < CH_E / 256; ++it) {
            int dst = ei[N_EDGES + base + it * 256 + t];
            atomicAdd(&cnt[dst], 1);
        }
    } else if (bid < NB_CNT + NB_NODE) {
        __shared__ float us[12], ud[12];
        if (t < 12) {
            int i = t >> 2, h = t & 3;
            float s = 0.f;
            #pragma unroll
            for (int c = 0; c < 32; ++c)
                s += W_gat[i * 128 + h * 32 + c] * att_src[h * 32 + c];
            us[t] = s;
        } else if (t < 24) {
            int q = t - 12; int i = q >> 2, h = q & 3;
            float s = 0.f;
            #pragma unroll
            for (int c = 0; c < 32; ++c)
                s += W_gat[i * 128 + h * 32 + c] * att_dst[h * 32 + c];
            ud[q] = s;
        }
        __syncthreads();
        int base = (bid - NB_CNT) * 2048;
        #pragma unroll 1
        for (int i = 0; i < 8; ++i) {
            int n = base + i * 256 + t;
            if (n >= N_NODES) break;
            float x0 = x[n * 3 + 0], x1 = x[n * 3 + 1], x2 = x[n * 3 + 2];
            float s[4], d[4];
            #pragma unroll
            for (int h = 0; h < 4; ++h) {
                s[h] = x0 * us[h] + x1 * us[4 + h] + x2 * us[8 + h];
                d[h] = x0 * ud[h] + x1 * ud[4 + h] + x2 * ud[8 + h];
            }
            a_src[n] = make_float4(s[0], s[1], s[2], s[3]);
            a_dst[n] = make_float4(d[0], d[1], d[2], d[3]);
        }
    } else if (bid == NB_CNT + NB_NODE) {
        if (t < 28) {
            int d = t >> 2, h = t & 3;
            float s = 0.f;
            #pragma unroll
            for (int c = 0; c < 32; ++c)
                s += W_edge[d * 128 + h * 32 + c] * att_edge[h * 32 + c];
            v[t] = s;
        }
    } else if (bid == NB_CNT + NB_NODE + 1) {
        // W1T bf16 hi/lo planes: W1T[n][k] = W1[k][n]
        #pragma unroll 4
        for (int i = 0; i < 64; ++i) {
            int idx = i * 256 + t;             // 16384
            int n = idx >> 7, k = idx & 127;
            float vv = W1[k * 128 + n];
            uint32_t hi = f2bf(vv);
            uint32_t lo = f2bf(vv - bflo(hi));
            W1T_hi[idx] = (uint16_t)hi;
            W1T_lo[idx] = (uint16_t)lo;
        }
    } else {
        // W2T bf16 hi/lo planes: W2T[j][k] = W2[k][j]
        #pragma unroll 4
        for (int i = 0; i < 16; ++i) {
            int idx = i * 256 + t;             // 4096
            int j = idx >> 7, k = idx & 127;
            float vv = W2[k * 32 + j];
            uint32_t hi = f2bf(vv);
            uint32_t lo = f2bf(vv - bflo(hi));
            W2T_hi[idx] = (uint16_t)hi;
            W2T_lo[idx] = (uint16_t)lo;
        }
    }
}

// per-bucket sum of cnt -> bsum (replaces the 25MB hist reduction)
__global__ __launch_bounds__(256) void k_bsum(const int* __restrict__ cnt,
                                              int* __restrict__ bsum) {
    __shared__ int red[256];
    int t = threadIdx.x;
    int i = blockIdx.x * 256 + t;
    red[t] = (i < N_NODES) ? cnt[i] : 0;
    __syncthreads();
    #pragma unroll
    for (int s = 128; s > 0; s >>= 1) {
        if (t < s) red[t] += red[t + s];
        __syncthreads();
    }
    if (t == 0) bsum[blockIdx.x] = red[0];
}

// single tiny block: exclusive scan of 196 bucket sums -> bbase[0..196]
__global__ __launch_bounds__(256) void k_scanb(const int* __restrict__ bsum,
                                               int* __restrict__ bbase) {
    __shared__ int sh[256];
    int t = threadIdx.x;
    int vv = (t < NBUCK) ? bsum[t] : 0;
    sh[t] = vv;
    __syncthreads();
    #pragma unroll
    for (int off = 1; off < 256; off <<= 1) {
        int xv = (t >= off) ? sh[t - off] : 0;
        __syncthreads();
        sh[t] += xv;
        __syncthreads();
    }
    if (t < NBUCK) bbase[t] = sh[t] - vv;      // exclusive
    if (t == 255) bbase[NBUCK] = sh[255];      // grand total (= N_EDGES)
}

// per-bucket local scan: rowptr slice + bcur (phase-1 bucket cursors)
__global__ __launch_bounds__(256) void k_local(const int* __restrict__ cnt,
                                               const int* __restrict__ bbase,
                                               int* __restrict__ rowptr,
                                               int* __restrict__ bcur) {
    __shared__ int sh[256];
    int b = blockIdx.x, t = threadIdx.x;
    int i = b * 256 + t;
    int vv = (i < N_NODES) ? cnt[i] : 0;
    sh[t] = vv;
    __syncthreads();
    #pragma unroll
    for (int off = 1; off < 256; off <<= 1) {
        int xv = (t >= off) ? sh[t - off] : 0;
        __syncthreads();
        sh[t] += xv;
        __syncthreads();
    }
    int base = bbase[b];
    if (i < N_NODES) rowptr[i] = base + sh[t] - vv;
    if (t == 0) bcur[b] = base;
    if (b == 0 && t == 0) rowptr[N_NODES] = bbase[NBUCK];
}

// scatter: compute records (comb = ae + a_src, 4xfp8 ae in pad word,
// dst&255 in bits 16..23 of the src word), stage bucket-partitioned.
// LDS-bucket-sorted copy-out (runs of ~10 -> fewer store transactions).
__global__ __launch_bounds__(512) void k_scat1(const int* __restrict__ ei,
                                               const float* __restrict__ edge_attr,
                                               const float* __restrict__ v,
                                               const float4* __restrict__ a_src,
                                               int* __restrict__ bcur,
                                               uint4* __restrict__ stg) {
    __shared__ int bh[NBUCK];        // per-block bucket histogram
    __shared__ int bg[NBUCK];        // this block's global base per bucket
    __shared__ int bl[NBUCK];        // local cursor per bucket
    __shared__ int bo[NBUCK];        // block-local exclusive offset per bucket
    __shared__ int sct[256];         // scan temp
    __shared__ u32x4 lrec[P1_EPB];   // bucket-sorted records (32KB)
    __shared__ int gaddr[P1_EPB];    // global slot per record (8KB)
    int t = threadIdx.x;
    float vsr[28];
    #pragma unroll
    for (int i = 0; i < 28; ++i) vsr[i] = v[i];   // uniform addr -> s_load

    for (int i = t; i < NBUCK; i += P1_T) bh[i] = 0;
    __syncthreads();

    int e0 = blockIdx.x * P1_EPB + t * 4;          // 4 consecutive edges
    bool act = (e0 < N_EDGES);                     // tail is a multiple of 4
    int dst[4];
    uint4 rec[4];
    if (act) {
        int4 s4 = *(const int4*)&ei[e0];
        int4 d4 = *(const int4*)&ei[N_EDGES + e0];
        int srcv[4] = {s4.x, s4.y, s4.z, s4.w};
        dst[0] = d4.x; dst[1] = d4.y; dst[2] = d4.z; dst[3] = d4.w;

        float4 as4[4];
        #pragma unroll
        for (int q = 0; q < 4; ++q)
            as4[q] = a_src[srcv[q]];               // L2-resident 800KB table

        const float4* ea4 = (const float4*)&edge_attr[e0 * 7];
        float ea[28];
        #pragma unroll
        for (int i = 0; i < 7; ++i) {
            float4 vv = ea4[i];
            ea[i * 4 + 0] = vv.x; ea[i * 4 + 1] = vv.y;
            ea[i * 4 + 2] = vv.z; ea[i * 4 + 3] = vv.w;
        }

        #pragma unroll
        for (int q = 0; q < 4; ++q) {
            float asv[4] = {as4[q].x, as4[q].y, as4[q].z, as4[q].w};
            float comb[4];
            uint32_t ae8 = 0;
            #pragma unroll
            for (int h = 0; h < 4; ++h) {
                float aeh = 0.f;
                #pragma unroll
                for (int d = 0; d < 7; ++d) aeh += ea[q * 7 + d] * vsr[d * 4 + h];
                ae8 |= f2e4m3(aeh) << (h * 8);
                comb[h] = aeh + asv[h];
            }
            rec[q] = make_uint4(pack2(comb[0], comb[1]), pack2(comb[2], comb[3]),
                                (uint32_t)srcv[q] | ((uint32_t)(dst[q] & 255) << 16),
                                ae8);
            atomicAdd(&bh[dst[q] >> 8], 1);
        }
    }
    __syncthreads();
    // block-local exclusive scan of bh (196 -> 256-wide Hillis-Steele)
    int hv = 0;
    if (t < 256) { hv = (t < NBUCK) ? bh[t] : 0; sct[t] = hv; }
    __syncthreads();
    #pragma unroll
    for (int off = 1; off < 256; off <<= 1) {
        int xv = 0;
        if (t < 256 && t >= off) xv = sct[t - off];
        __syncthreads();
        if (t < 256) sct[t] += xv;
        __syncthreads();
    }
    if (t < NBUCK) {
        bo[t] = sct[t] - hv;                       // local exclusive base
        bg[t] = hv ? atomicAdd(&bcur[t], hv) : 0;  // global run base
        bl[t] = 0;
    }
    __syncthreads();
    if (act) {
        #pragma unroll
        for (int q = 0; q < 4; ++q) {
            int bk = dst[q] >> 8;
            int off = atomicAdd(&bl[bk], 1);       // fast LDS cursor
            int slot = bo[bk] + off;
            lrec[slot] = (u32x4){rec[q].x, rec[q].y, rec[q].z, rec[q].w};
            gaddr[slot] = bg[bk] + off;
        }
    }
    __syncthreads();
    int total = sct[255];                          // records in this block
    for (int s = t; s < total; s += P1_T) {
        u32x4 r = lrec[s];
        stg[gaddr[s]] = make_uint4(r.x, r.y, r.z, r.w);
    }
}

// fused sort+gather: one 1024-thread block per bucket. The bucket's ~8192
// records (<= CAP, +8.5 sigma margin) are node-sorted INTO LDS (one ds
// atomicSub per record), then each of 16 waves gathers 16 nodes reading
// records straight from LDS — csr never touches HBM (saves 51MB round-trip).
// Gather math = k_gather v3 (x-aggregation, projection through W_gat after).
__global__ __launch_bounds__(1024) void k_scat2g(const int* __restrict__ rowptr,
                                                 const int* __restrict__ bbase,
                                                 const uint4* __restrict__ stg,
                                                 const float* __restrict__ x,
                                                 const float* __restrict__ a_src,
                                                 const float* __restrict__ a_dst,
                                                 const float* __restrict__ W_gat,
                                                 const float* __restrict__ bias_gat,
                                                 float2* __restrict__ h_buf) {
    __shared__ int rp[257];
    __shared__ int lcnt[256];
    __shared__ u32x4 lrec[CAP];      // 140KB bucket-local CSR
    int b = blockIdx.x, t = threadIdx.x;
    int n0 = b << 8;
    int nn = min(256, N_NODES - n0);
    int base = bbase[b];
    for (int i = t; i <= nn; i += 1024) rp[i] = rowptr[n0 + i] - base;
    __syncthreads();
    for (int i = t; i < nn; i += 1024) lcnt[i] = rp[i + 1] - rp[i];
    __syncthreads();
    int total = rp[nn];

    // phase 1: node-sort the stg slice into LDS (coalesced read, ~8 rec/thread)
    for (int e = t; e < total; e += 1024) {
        uint4 r = stg[base + e];
        int dl = (int)((r.z >> 16) & 0xFFu);
        int c = atomicSub(&lcnt[dl], 1);
        int slot = rp[dl] + c - 1;
        if (slot < CAP) lrec[slot] = (u32x4){r.x, r.y, r.z, r.w};
    }
    __syncthreads();

    // phase 2: wave wv gathers nodes wv*16 .. wv*16+15 from LDS
    int wv = t >> 6, l = t & 63;
    int h = l & 3;                 // aggregation head
    int slot = l >> 2;             // edge slot 0..15
    int c0 = 2 * l;
    float w00 = W_gat[c0],       w01 = W_gat[c0 + 1];
    float w10 = W_gat[128 + c0], w11 = W_gat[128 + c0 + 1];
    float w20 = W_gat[256 + c0], w21 = W_gat[256 + c0 + 1];
    float2 bia = ((const float2*)bias_gat)[l];

    #pragma unroll 1
    for (int j = 0; j < 16; ++j) {
        int i = wv * 16 + j;
        if (i >= nn) break;                        // wave-uniform
        int n = n0 + i;
        int start = rp[i], end = rp[i + 1];
        int deg = end - start;
        float ad_n = a_dst[n * 4 + h];
        float as_n = a_src[n * 4 + h];
        float sx0 = 0.f, sx1 = 0.f, sx2 = 0.f, den = 0.f, aes = 0.f;

        for (int p0 = start; p0 < end; p0 += 16) {
            int e = p0 + slot;
            float w = 0.f, ae = 0.f;
            int src = n;
            if (e < end) {
                u32x4 rc = lrec[e];
                uint32_t aw = (h < 2) ? rc.x : rc.y;
                float comb = (h & 1) ? bfhi(aw) : bflo(aw);   // ae + a_src[src]
                ae = e4m32f((rc.w >> (h * 8)) & 0xffu);
                src = (int)(rc.z & 0xFFFFu);
                float al = comb + ad_n;
                al = al > 0.f ? al : NEG_SLOPE * al;
                w = __expf(al);
            }
            const float* xr = x + src * 3;                    // L2-hot table
            sx0 += w * xr[0];
            sx1 += w * xr[1];
            sx2 += w * xr[2];
            den += w;
            aes += ae;
        }

        // allreduce across the 16 slots (lanes with equal l&3)
        #pragma unroll
        for (int m = 4; m <= 32; m <<= 1) {
            sx0 += __shfl_xor(sx0, m);
            sx1 += __shfl_xor(sx1, m);
            sx2 += __shfl_xor(sx2, m);
            den += __shfl_xor(den, m);
            aes += __shfl_xor(aes, m);
        }

        // self loop: edge_attr = mean of incoming aeh
        float xn0 = x[n * 3], xn1 = x[n * 3 + 1], xn2 = x[n * 3 + 2];
        float invd = (deg > 0) ? (1.0f / (float)deg) : 1.0f;
        float alS = as_n + ad_n + aes * invd;
        alS = alS > 0.f ? alS : NEG_SLOPE * alS;
        float wS = __expf(alS);
        sx0 += wS * xn0; sx1 += wS * xn1; sx2 += wS * xn2;
        den += wS;

        // lane l needs head l>>4 totals (all lanes hold their head's total)
        int sb = (l >> 4) << 2;
        float t0 = bpermf(sb, sx0);
        float t1 = bpermf(sb, sx1);
        float t2 = bpermf(sb, sx2);
        float td = bpermf(sb, den);

        float r = 1.0f / td;
        float o0 = (t0 * w00 + t1 * w10 + t2 * w20) * r + bia.x;
        float o1 = (t0 * w01 + t1 * w11 + t2 * w21) * r + bia.y;
        o0 = o0 > 0.f ? o0 : (__expf(o0) - 1.0f);   // ELU
        o1 = o1 > 0.f ? o1 : (__expf(o1) - 1.0f);
        h_buf[(size_t)n * 64 + l] = make_float2(o0, o1);
    }
}

// MFMA MLP: 32 rows/block, 4 waves. bf16 hi/lo split (3-term) for ~fp32
// accuracy at matrix-pipe rate. LDS planes [32][136] bf16 (row stride 272B).
__global__ __launch_bounds__(256) void k_mlp(const float* __restrict__ h_buf,
                                             const uint16_t* __restrict__ W1T_hi,
                                             const uint16_t* __restrict__ W1T_lo,
                                             const uint16_t* __restrict__ W2T_hi,
                                             const uint16_t* __restrict__ W2T_lo,
                                             const float* __restrict__ b1,
                                             const float* __restrict__ prelu_a,
                                             const float* __restrict__ b2,
                                             float* __restrict__ out) {
    __shared__ uint16_t hHi[32 * 136];
    __shared__ uint16_t hLo[32 * 136];
    __shared__ uint16_t h1Hi[32 * 136];
    __shared__ uint16_t h1Lo[32 * 136];
    int t = threadIdx.x;
    int nb = blockIdx.x * 32;

    // stage h rows -> bf16 hi/lo planes
    const float4* hb4 = (const float4*)(h_buf + (size_t)nb * 128);
    #pragma unroll
    for (int i = 0; i < 4; ++i) {
        int idx = i * 256 + t;             // float4 index, 1024 total
        int row = idx >> 5, c4 = idx & 31;
        float4 v = make_float4(0.f, 0.f, 0.f, 0.f);
        if (nb + row < N_NODES) v = hb4[idx];
        float xs[4] = {v.x, v.y, v.z, v.w};
        uint32_t hi[4], lo[4];
        #pragma unroll
        for (int j = 0; j < 4; ++j) {
            hi[j] = f2bf(xs[j]);
            lo[j] = f2bf(xs[j] - bflo(hi[j]));
        }
        uint32_t bo = row * 272 + c4 * 8;
        *(uint2*)((char*)hHi + bo) = make_uint2(hi[0] | (hi[1] << 16), hi[2] | (hi[3] << 16));
        *(uint2*)((char*)hLo + bo) = make_uint2(lo[0] | (lo[1] << 16), lo[2] | (lo[3] << 16));
    }
    __syncthreads();

    int w = t >> 6, l = t & 63;
    int lr = l & 15, lg = l >> 4;          // frag row/col lane, k-group
    // ---- layer 1: wave w -> col-tiles {2w, 2w+1}, both row-tiles ----
    float bb0 = b1[(2 * w) * 16 + lr];
    float bb1 = b1[(2 * w + 1) * 16 + lr];
    f32x4 acc[2][2];
    #pragma unroll
    for (int rt = 0; rt < 2; ++rt) {
        acc[rt][0] = (f32x4){bb0, bb0, bb0, bb0};
        acc[rt][1] = (f32x4){bb1, bb1, bb1, bb1};
    }
    #pragma unroll
    for (int s = 0; s < 4; ++s) {
        int koff = s * 64 + lg * 16;       // byte offset of k-chunk
        bf16x8 a_hi[2], a_lo[2], b_hi[2], b_lo[2];
        #pragma unroll
        for (int rt = 0; rt < 2; ++rt) {
            int ro = (rt * 16 + lr) * 272 + koff;
            a_hi[rt] = *(const bf16x8*)((const char*)hHi + ro);
            a_lo[rt] = *(const bf16x8*)((const char*)hLo + ro);
        }
        #pragma unroll
        for (int c = 0; c < 2; ++c) {
            int go = ((2 * w + c) * 16 + lr) * 256 + koff;
            b_hi[c] = *(const bf16x8*)((const char*)W1T_hi + go);
            b_lo[c] = *(const bf16x8*)((const char*)W1T_lo + go);
        }
        #pragma unroll
        for (int rt = 0; rt < 2; ++rt)
            #pragma unroll
            for (int c = 0; c < 2; ++c) {
                acc[rt][c] = __builtin_amdgcn_mfma_f32_16x16x32_bf16(a_hi[rt], b_hi[c], acc[rt][c], 0, 0, 0);
                acc[rt][c] = __builtin_amdgcn_mfma_f32_16x16x32_bf16(a_hi[rt], b_lo[c], acc[rt][c], 0, 0, 0);
                acc[rt][c] = __builtin_amdgcn_mfma_f32_16x16x32_bf16(a_lo[rt], b_hi[c], acc[rt][c], 0, 0, 0);
            }
    }
    // PReLU + re-split -> h1 planes
    float pa = prelu_a[0];
    #pragma unroll
    for (int rt = 0; rt < 2; ++rt)
        #pragma unroll
        for (int c = 0; c < 2; ++c) {
            int n = (2 * w + c) * 16 + lr;
            #pragma unroll
            for (int r = 0; r < 4; ++r) {
                float vv = acc[rt][c][r];
                vv = vv > 0.f ? vv : pa * vv;
                uint32_t hi = f2bf(vv);
                uint32_t lo = f2bf(vv - bflo(hi));
                int m = rt * 16 + lg * 4 + r;
                uint32_t bo = m * 272 + n * 2;
                *(uint16_t*)((char*)h1Hi + bo) = (uint16_t)hi;
                *(uint16_t*)((char*)h1Lo + bo) = (uint16_t)lo;
            }
        }
    __syncthreads();
    // ---- layer 2: wave w -> tile (rt = w&1, ct = w>>1) ----
    int rt2 = w & 1, ct2 = w >> 1;
    float bb2 = b2[ct2 * 16 + lr];
    f32x4 acc2 = (f32x4){bb2, bb2, bb2, bb2};
    #pragma unroll
    for (int s = 0; s < 4; ++s) {
        int koff = s * 64 + lg * 16;
        int ro = (rt2 * 16 + lr) * 272 + koff;
        bf16x8 a_hi = *(const bf16x8*)((const char*)h1Hi + ro);
        bf16x8 a_lo = *(const bf16x8*)((const char*)h1Lo + ro);
        int go = (ct2 * 16 + lr) * 256 + koff;
        bf16x8 w2h = *(const bf16x8*)((const char*)W2T_hi + go);
        bf16x8 w2l = *(const bf16x8*)((const char*)W2T_lo + go);
        acc2 = __builtin_amdgcn_mfma_f32_16x16x32_bf16(a_hi, w2h, acc2, 0, 0, 0);
        acc2 = __builtin_amdgcn_mfma_f32_16x16x32_bf16(a_hi, w2l, acc2, 0, 0, 0);
        acc2 = __builtin_amdgcn_mfma_f32_16x16x32_bf16(a_lo, w2h, acc2, 0, 0, 0);
    }
    #pragma unroll
    for (int r = 0; r < 4; ++r) {
        int m = rt2 * 16 + lg * 4 + r;
        if (nb + m < N_NODES)
            out[(size_t)(nb + m) * 32 + ct2 * 16 + lr] = acc2[r];
    }
}

// ---------------------------------------------------------------- launch

extern "C" void kernel_launch(void* const* d_in, const int* in_sizes, int n_in,
                              void* d_out, int out_size, void* d_ws, size_t ws_size,
                              hipStream_t stream) {
    const float* x        = (const float*)d_in[0];
    const int*   ei       = (const int*)d_in[1];     // int32 per harness contract
    const float* edge_attr= (const float*)d_in[2];
    const float* W_gat    = (const float*)d_in[3];
    const float* att_src  = (const float*)d_in[4];
    const float* att_dst  = (const float*)d_in[5];
    const float* W_edge   = (const float*)d_in[6];
    const float* att_edge = (const float*)d_in[7];
    const float* bias_gat = (const float*)d_in[8];
    const float* W1       = (const float*)d_in[9];
    const float* b1       = (const float*)d_in[10];
    const float* prelu_a  = (const float*)d_in[11];
    const float* W2       = (const float*)d_in[12];
    const float* b2       = (const float*)d_in[13];
    float*       out      = (float*)d_out;

    char* base = (char*)d_ws;
    size_t off = 0;
    auto alloc = [&](size_t bytes) -> void* {
        void* p = base + off;
        off = (off + bytes + 255) & ~(size_t)255;
        return p;
    };
    int*      cnt     = (int*)     alloc((size_t)N_NODES * 4);
    int*      rowptr  = (int*)     alloc((size_t)(N_NODES + 1) * 4);
    int*      bcur    = (int*)     alloc((size_t)NBUCK * 4);
    int*      bsum    = (int*)     alloc((size_t)NBUCK * 4);
    int*      bbase   = (int*)     alloc((size_t)(NBUCK + 1) * 4);
    float*    v       = (float*)   alloc(32 * 4);
    uint16_t* W1T_hi  = (uint16_t*)alloc((size_t)128 * 128 * 2);
    uint16_t* W1T_lo  = (uint16_t*)alloc((size_t)128 * 128 * 2);
    uint16_t* W2T_hi  = (uint16_t*)alloc((size_t)32 * 128 * 2);
    uint16_t* W2T_lo  = (uint16_t*)alloc((size_t)32 * 128 * 2);
    float*    a_src   = (float*)   alloc((size_t)N_NODES * 4 * 4);
    float*    a_dst   = (float*)   alloc((size_t)N_NODES * 4 * 4);
    float*    h_buf   = (float*)   alloc((size_t)N_NODES * 128 * 4);
    uint4*    stg     = (uint4*)   alloc((size_t)N_EDGES * 16);

    k_zero  <<<(N_NODES + 1023) / 1024, 1024, 0, stream>>>(cnt);
    k_pre   <<<NB_PRE, 256, 0, stream>>>(x, ei, W_gat, att_src, att_dst,
                                         W_edge, att_edge, W1, W2, cnt,
                                         (float4*)a_src, (float4*)a_dst, v,
                                         W1T_hi, W1T_lo, W2T_hi, W2T_lo);
    k_bsum  <<<NBUCK, 256, 0, stream>>>(cnt, bsum);
    k_scanb <<<1, 256, 0, stream>>>(bsum, bbase);
    k_local <<<NBUCK, 256, 0, stream>>>(cnt, bbase, rowptr, bcur);
    k_scat1 <<<P1_BLOCKS, P1_T, 0, stream>>>(
        ei, edge_attr, v, (const float4*)a_src, bcur, stg);
    k_scat2g<<<NBUCK, 1024, 0, stream>>>(
        rowptr, bbase, stg, x, a_src, a_dst, W_gat, bias_gat, (float2*)h_buf);
    k_mlp   <<<(N_NODES + 31) / 32, 256, 0, stream>>>(
        h_buf, W1T_hi, W1T_lo, W2T_hi, W2T_lo, b1, prelu_a, b2, out);
}

// Round 11
// 228.755 us; speedup vs baseline: 1.2135x; 1.2135x over previous
//
#include <hip/hip_runtime.h>
#include <cstdint>

#define N_NODES 50000
#define N_EDGES 1600000
#define NH 4
#define CC 32
#define HC 128          // NH*CC
#define LAT 32
#define NEG_SLOPE 0.2f

// k_pre role split: [node | v | w1t | w2t]  (no more degree histogram)
#define NB_NODE 25                       // node: 2048 nodes per block
#define NB_PRE  (NB_NODE + 3)            // +v +w1t +w2t

// bucket count kernel
#define NB_BC   250                      // 250 x 6400-edge chunks
#define CH_E    6400

// bucketed scatter: bucket = dst >> 8 (256 nodes / bucket)
#define NBUCK 196                        // ceil(50000/256)
#define P1_T  512
#define P1_EPB (P1_T * 4)                // 2048 edges per phase-1 block
#define P1_BLOCKS ((N_EDGES + P1_EPB - 1) / P1_EPB)   // 782
#define CAP  8960                        // LDS bucket capacity (mean 8192 + 8.5 sigma)

typedef uint32_t u32x4 __attribute__((ext_vector_type(4)));
typedef __bf16   bf16x8 __attribute__((ext_vector_type(8)));
typedef float    f32x4 __attribute__((ext_vector_type(4)));

// ---------------- bf16 helpers (RNE pack, shift-unpack) ----------------
__device__ __forceinline__ float bflo(uint32_t u) {
    union { uint32_t i; float f; } c; c.i = u << 16; return c.f;
}
__device__ __forceinline__ float bfhi(uint32_t u) {
    union { uint32_t i; float f; } c; c.i = u & 0xFFFF0000u; return c.f;
}
__device__ __forceinline__ uint32_t f2bf(float f) {
    union { float f; uint32_t i; } c; c.f = f;
    return (c.i + 0x7FFFu + ((c.i >> 16) & 1u)) >> 16;
}
__device__ __forceinline__ uint32_t pack2(float a, float b) {
    return f2bf(a) | (f2bf(b) << 16);
}
__device__ __forceinline__ float bpermf(int byteIdx, float v) {
    return __int_as_float(__builtin_amdgcn_ds_bpermute(byteIdx, __float_as_int(v)));
}
// fp8 e4m3fn pack/unpack (ae only feeds the self-loop mean -> 6% rel err ok)
__device__ __forceinline__ uint32_t f2e4m3(float x) {
    uint32_t u = __float_as_uint(x);
    uint32_t s = u >> 31;
    uint32_t mag = u & 0x7fffffffu;
    mag += 0x7ffffu + ((mag >> 20) & 1u);       // RNE at bit 20
    uint32_t e = mag >> 23;
    if (e < 121u) return s << 7;                // underflow -> 0
    uint32_t code = ((e - 120u) << 3) | ((mag >> 20) & 7u);
    if (code > 0x7Eu) code = 0x7Eu;             // clamp to 448
    return (s << 7) | code;
}
__device__ __forceinline__ float e4m32f(uint32_t b) {
    uint32_t e = (b >> 3) & 15u;
    if (e == 0u) return 0.f;
    return __uint_as_float(((b >> 7) << 31) | ((e + 120u) << 23) | ((b & 7u) << 20));
}

// ---------------------------------------------------------------- kernels

// zero the 196 bucket counters (tiny)
__global__ __launch_bounds__(256) void k_zero196(int* __restrict__ bsum) {
    int t = threadIdx.x;
    if (t < NBUCK) bsum[t] = 0;
}

// bucket-size count: per-block 196-bin LDS histogram, then ONE global
// atomicAdd per (block,bin) = 49K total atomics (vs round-10's 1.6M
// random global RMWs, the measured 74us failure). Per-node degrees are
// NOT counted globally at all — k_scat2g derives them from its own slice.
__global__ __launch_bounds__(256) void k_bcnt(const int* __restrict__ ei,
                                              int* __restrict__ bsum) {
    __shared__ int bh[NBUCK];
    int t = threadIdx.x;
    for (int i = t; i < NBUCK; i += 256) bh[i] = 0;
    __syncthreads();
    int base = blockIdx.x * CH_E;
    #pragma unroll 1
    for (int it = 0; it < CH_E / 256; ++it) {
        int dst = ei[N_EDGES + base + it * 256 + t];
        atomicAdd(&bh[dst >> 8], 1);
    }
    __syncthreads();
    for (int i = t; i < NBUCK; i += 256) {
        int h = bh[i];
        if (h) atomicAdd(&bsum[i], h);
    }
}

// front end: [node | v | w1t | w2t] by blockIdx range (28 blocks)
__global__ __launch_bounds__(256) void k_pre(const float* __restrict__ x,
                                             const float* __restrict__ W_gat,
                                             const float* __restrict__ att_src,
                                             const float* __restrict__ att_dst,
                                             const float* __restrict__ W_edge,
                                             const float* __restrict__ att_edge,
                                             const float* __restrict__ W1,
                                             const float* __restrict__ W2,
                                             float4* __restrict__ a_src,
                                             float4* __restrict__ a_dst,
                                             float* __restrict__ v,
                                             uint16_t* __restrict__ W1T_hi,
                                             uint16_t* __restrict__ W1T_lo,
                                             uint16_t* __restrict__ W2T_hi,
                                             uint16_t* __restrict__ W2T_lo) {
    int bid = blockIdx.x, t = threadIdx.x;
    if (bid < NB_NODE) {
        __shared__ float us[12], ud[12];
        if (t < 12) {
            int i = t >> 2, h = t & 3;
            float s = 0.f;
            #pragma unroll
            for (int c = 0; c < 32; ++c)
                s += W_gat[i * 128 + h * 32 + c] * att_src[h * 32 + c];
            us[t] = s;
        } else if (t < 24) {
            int q = t - 12; int i = q >> 2, h = q & 3;
            float s = 0.f;
            #pragma unroll
            for (int c = 0; c < 32; ++c)
                s += W_gat[i * 128 + h * 32 + c] * att_dst[h * 32 + c];
            ud[q] = s;
        }
        __syncthreads();
        int base = bid * 2048;
        #pragma unroll 1
        for (int i = 0; i < 8; ++i) {
            int n = base + i * 256 + t;
            if (n >= N_NODES) break;
            float x0 = x[n * 3 + 0], x1 = x[n * 3 + 1], x2 = x[n * 3 + 2];
            float s[4], d[4];
            #pragma unroll
            for (int h = 0; h < 4; ++h) {
                s[h] = x0 * us[h] + x1 * us[4 + h] + x2 * us[8 + h];
                d[h] = x0 * ud[h] + x1 * ud[4 + h] + x2 * ud[8 + h];
            }
            a_src[n] = make_float4(s[0], s[1], s[2], s[3]);
            a_dst[n] = make_float4(d[0], d[1], d[2], d[3]);
        }
    } else if (bid == NB_NODE) {
        if (t < 28) {
            int d = t >> 2, h = t & 3;
            float s = 0.f;
            #pragma unroll
            for (int c = 0; c < 32; ++c)
                s += W_edge[d * 128 + h * 32 + c] * att_edge[h * 32 + c];
            v[t] = s;
        }
    } else if (bid == NB_NODE + 1) {
        // W1T bf16 hi/lo planes: W1T[n][k] = W1[k][n]
        #pragma unroll 4
        for (int i = 0; i < 64; ++i) {
            int idx = i * 256 + t;             // 16384
            int n = idx >> 7, k = idx & 127;
            float vv = W1[k * 128 + n];
            uint32_t hi = f2bf(vv);
            uint32_t lo = f2bf(vv - bflo(hi));
            W1T_hi[idx] = (uint16_t)hi;
            W1T_lo[idx] = (uint16_t)lo;
        }
    } else {
        // W2T bf16 hi/lo planes: W2T[j][k] = W2[k][j]
        #pragma unroll 4
        for (int i = 0; i < 16; ++i) {
            int idx = i * 256 + t;             // 4096
            int j = idx >> 7, k = idx & 127;
            float vv = W2[k * 32 + j];
            uint32_t hi = f2bf(vv);
            uint32_t lo = f2bf(vv - bflo(hi));
            W2T_hi[idx] = (uint16_t)hi;
            W2T_lo[idx] = (uint16_t)lo;
        }
    }
}

// single tiny block: exclusive scan of 196 bucket sums -> bbase[0..196], bcur
__global__ __launch_bounds__(256) void k_scanb(const int* __restrict__ bsum,
                                               int* __restrict__ bbase,
                                               int* __restrict__ bcur) {
    __shared__ int sh[256];
    int t = threadIdx.x;
    int vv = (t < NBUCK) ? bsum[t] : 0;
    sh[t] = vv;
    __syncthreads();
    #pragma unroll
    for (int off = 1; off < 256; off <<= 1) {
        int xv = (t >= off) ? sh[t - off] : 0;
        __syncthreads();
        sh[t] += xv;
        __syncthreads();
    }
    if (t < NBUCK) { bbase[t] = sh[t] - vv; bcur[t] = sh[t] - vv; }
    if (t == 255) bbase[NBUCK] = sh[255];      // grand total (= N_EDGES)
}

// scatter: compute records (comb = ae + a_src, 4xfp8 ae in pad word,
// dst&255 in bits 16..23 of the src word), stage bucket-partitioned.
// LDS-bucket-sorted copy-out + 1-byte dst sidecar (stg8) so the fused
// gather can count per-node degrees with a cheap coalesced byte pass.
__global__ __launch_bounds__(512) void k_scat1(const int* __restrict__ ei,
                                               const float* __restrict__ edge_attr,
                                               const float* __restrict__ v,
                                               const float4* __restrict__ a_src,
                                               int* __restrict__ bcur,
                                               uint4* __restrict__ stg,
                                               uint8_t* __restrict__ stg8) {
    __shared__ int bh[NBUCK];        // per-block bucket histogram
    __shared__ int bg[NBUCK];        // this block's global base per bucket
    __shared__ int bl[NBUCK];        // local cursor per bucket
    __shared__ int bo[NBUCK];        // block-local exclusive offset per bucket
    __shared__ int sct[256];         // scan temp
    __shared__ u32x4 lrec[P1_EPB];   // bucket-sorted records (32KB)
    __shared__ int gaddr[P1_EPB];    // global slot per record (8KB)
    int t = threadIdx.x;
    float vsr[28];
    #pragma unroll
    for (int i = 0; i < 28; ++i) vsr[i] = v[i];   // uniform addr -> s_load

    for (int i = t; i < NBUCK; i += P1_T) bh[i] = 0;
    __syncthreads();

    int e0 = blockIdx.x * P1_EPB + t * 4;          // 4 consecutive edges
    bool act = (e0 < N_EDGES);                     // tail is a multiple of 4
    int dst[4];
    uint4 rec[4];
    if (act) {
        int4 s4 = *(const int4*)&ei[e0];
        int4 d4 = *(const int4*)&ei[N_EDGES + e0];
        int srcv[4] = {s4.x, s4.y, s4.z, s4.w};
        dst[0] = d4.x; dst[1] = d4.y; dst[2] = d4.z; dst[3] = d4.w;

        float4 as4[4];
        #pragma unroll
        for (int q = 0; q < 4; ++q)
            as4[q] = a_src[srcv[q]];               // L2-resident 800KB table

        const float4* ea4 = (const float4*)&edge_attr[e0 * 7];
        float ea[28];
        #pragma unroll
        for (int i = 0; i < 7; ++i) {
            float4 vv = ea4[i];
            ea[i * 4 + 0] = vv.x; ea[i * 4 + 1] = vv.y;
            ea[i * 4 + 2] = vv.z; ea[i * 4 + 3] = vv.w;
        }

        #pragma unroll
        for (int q = 0; q < 4; ++q) {
            float asv[4] = {as4[q].x, as4[q].y, as4[q].z, as4[q].w};
            float comb[4];
            uint32_t ae8 = 0;
            #pragma unroll
            for (int h = 0; h < 4; ++h) {
                float aeh = 0.f;
                #pragma unroll
                for (int d = 0; d < 7; ++d) aeh += ea[q * 7 + d] * vsr[d * 4 + h];
                ae8 |= f2e4m3(aeh) << (h * 8);
                comb[h] = aeh + asv[h];
            }
            rec[q] = make_uint4(pack2(comb[0], comb[1]), pack2(comb[2], comb[3]),
                                (uint32_t)srcv[q] | ((uint32_t)(dst[q] & 255) << 16),
                                ae8);
            atomicAdd(&bh[dst[q] >> 8], 1);
        }
    }
    __syncthreads();
    // block-local exclusive scan of bh (196 -> 256-wide Hillis-Steele)
    int hv = 0;
    if (t < 256) { hv = (t < NBUCK) ? bh[t] : 0; sct[t] = hv; }
    __syncthreads();
    #pragma unroll
    for (int off = 1; off < 256; off <<= 1) {
        int xv = 0;
        if (t < 256 && t >= off) xv = sct[t - off];
        __syncthreads();
        if (t < 256) sct[t] += xv;
        __syncthreads();
    }
    if (t < NBUCK) {
        bo[t] = sct[t] - hv;                       // local exclusive base
        bg[t] = hv ? atomicAdd(&bcur[t], hv) : 0;  // global run base
        bl[t] = 0;
    }
    __syncthreads();
    if (act) {
        #pragma unroll
        for (int q = 0; q < 4; ++q) {
            int bk = dst[q] >> 8;
            int off = atomicAdd(&bl[bk], 1);       // fast LDS cursor
            int slot = bo[bk] + off;
            lrec[slot] = (u32x4){rec[q].x, rec[q].y, rec[q].z, rec[q].w};
            gaddr[slot] = bg[bk] + off;
        }
    }
    __syncthreads();
    int total = sct[255];                          // records in this block
    for (int s = t; s < total; s += P1_T) {
        u32x4 r = lrec[s];
        int ga = gaddr[s];
        stg[ga] = make_uint4(r.x, r.y, r.z, r.w);
        stg8[ga] = (uint8_t)(r.z >> 16);
    }
}

// fused sort+gather: one 1024-thread block per bucket.
// phase 0: count this bucket's per-node degrees from the 1-byte sidecar
//          (coalesced, ~8KB) + 256-wide local scan -> rp[] (rowptr is gone)
// phase 1: node-sort the ~8192 records into LDS (one ds atomicSub each)
// phase 2: per-wave node gather straight from LDS (k_gather v3 math:
//          aggregate raw x, project through W_gat after; self-loop mean ae).
__global__ __launch_bounds__(1024) void k_scat2g(const int* __restrict__ bbase,
                                                 const uint4* __restrict__ stg,
                                                 const uint8_t* __restrict__ stg8,
                                                 const float* __restrict__ x,
                                                 const float* __restrict__ a_src,
                                                 const float* __restrict__ a_dst,
                                                 const float* __restrict__ W_gat,
                                                 const float* __restrict__ bias_gat,
                                                 float2* __restrict__ h_buf) {
    __shared__ int rp[257];
    __shared__ int lcnt[256];
    __shared__ int dcnt[256];
    __shared__ u32x4 lrec[CAP];      // 140KB bucket-local CSR
    int b = blockIdx.x, t = threadIdx.x;
    int n0 = b << 8;
    int nn = min(256, N_NODES - n0);
    int base = bbase[b];
    int total = bbase[b + 1] - base;
    if (t < 256) dcnt[t] = 0;
    __syncthreads();

    // phase 0: degree count from sidecar
    for (int e = t; e < total; e += 1024)
        atomicAdd(&dcnt[(int)stg8[base + e]], 1);
    __syncthreads();
    // 256-wide inclusive scan -> exclusive rp[0..256]
    if (t < 256) rp[t] = dcnt[t];
    __syncthreads();
    #pragma unroll
    for (int off = 1; off < 256; off <<= 1) {
        int xv = 0;
        if (t < 256 && t >= off) xv = rp[t - off];
        __syncthreads();
        if (t < 256) rp[t] += xv;
        __syncthreads();
    }
    int incl = (t < 256) ? rp[t] : 0;
    __syncthreads();
    if (t < 256) {
        rp[t + 1] = incl;              // rp[1..256] = inclusive prefix
        if (t == 0) rp[0] = 0;
        lcnt[t] = dcnt[t];
    }
    __syncthreads();

    // phase 1: node-sort the stg slice into LDS (coalesced read)
    for (int e = t; e < total; e += 1024) {
        uint4 r = stg[base + e];
        int dl = (int)((r.z >> 16) & 0xFFu);
        int c = atomicSub(&lcnt[dl], 1);
        int slot = rp[dl] + c - 1;
        if (slot < CAP) lrec[slot] = (u32x4){r.x, r.y, r.z, r.w};
    }
    __syncthreads();

    // phase 2: wave wv gathers nodes wv*16 .. wv*16+15 from LDS
    int wv = t >> 6, l = t & 63;
    int h = l & 3;                 // aggregation head
    int slot = l >> 2;             // edge slot 0..15
    int c0 = 2 * l;
    float w00 = W_gat[c0],       w01 = W_gat[c0 + 1];
    float w10 = W_gat[128 + c0], w11 = W_gat[128 + c0 + 1];
    float w20 = W_gat[256 + c0], w21 = W_gat[256 + c0 + 1];
    float2 bia = ((const float2*)bias_gat)[l];

    #pragma unroll 1
    for (int j = 0; j < 16; ++j) {
        int i = wv * 16 + j;
        if (i >= nn) break;                        // wave-uniform
        int n = n0 + i;
        int start = rp[i], end = rp[i + 1];
        int deg = end - start;
        float ad_n = a_dst[n * 4 + h];
        float as_n = a_src[n * 4 + h];
        float sx0 = 0.f, sx1 = 0.f, sx2 = 0.f, den = 0.f, aes = 0.f;

        for (int p0 = start; p0 < end; p0 += 16) {
            int e = p0 + slot;
            float w = 0.f, ae = 0.f;
            int src = n;
            if (e < end) {
                u32x4 rc = lrec[e];
                uint32_t aw = (h < 2) ? rc.x : rc.y;
                float comb = (h & 1) ? bfhi(aw) : bflo(aw);   // ae + a_src[src]
                ae = e4m32f((rc.w >> (h * 8)) & 0xffu);
                src = (int)(rc.z & 0xFFFFu);
                float al = comb + ad_n;
                al = al > 0.f ? al : NEG_SLOPE * al;
                w = __expf(al);
            }
            const float* xr = x + src * 3;                    // L2-hot table
            sx0 += w * xr[0];
            sx1 += w * xr[1];
            sx2 += w * xr[2];
            den += w;
            aes += ae;
        }

        // allreduce across the 16 slots (lanes with equal l&3)
        #pragma unroll
        for (int m = 4; m <= 32; m <<= 1) {
            sx0 += __shfl_xor(sx0, m);
            sx1 += __shfl_xor(sx1, m);
            sx2 += __shfl_xor(sx2, m);
            den += __shfl_xor(den, m);
            aes += __shfl_xor(aes, m);
        }

        // self loop: edge_attr = mean of incoming aeh
        float xn0 = x[n * 3], xn1 = x[n * 3 + 1], xn2 = x[n * 3 + 2];
        float invd = (deg > 0) ? (1.0f / (float)deg) : 1.0f;
        float alS = as_n + ad_n + aes * invd;
        alS = alS > 0.f ? alS : NEG_SLOPE * alS;
        float wS = __expf(alS);
        sx0 += wS * xn0; sx1 += wS * xn1; sx2 += wS * xn2;
        den += wS;

        // lane l needs head l>>4 totals (all lanes hold their head's total)
        int sb = (l >> 4) << 2;
        float t0 = bpermf(sb, sx0);
        float t1 = bpermf(sb, sx1);
        float t2 = bpermf(sb, sx2);
        float td = bpermf(sb, den);

        float r = 1.0f / td;
        float o0 = (t0 * w00 + t1 * w10 + t2 * w20) * r + bia.x;
        float o1 = (t0 * w01 + t1 * w11 + t2 * w21) * r + bia.y;
        o0 = o0 > 0.f ? o0 : (__expf(o0) - 1.0f);   // ELU
        o1 = o1 > 0.f ? o1 : (__expf(o1) - 1.0f);
        h_buf[(size_t)n * 64 + l] = make_float2(o0, o1);
    }
}

// MFMA MLP: 32 rows/block, 4 waves. bf16 hi/lo split (3-term) for ~fp32
// accuracy at matrix-pipe rate. LDS planes [32][136] bf16 (row stride 272B).
__global__ __launch_bounds__(256) void k_mlp(const float* __restrict__ h_buf,
                                             const uint16_t* __restrict__ W1T_hi,
                                             const uint16_t* __restrict__ W1T_lo,
                                             const uint16_t* __restrict__ W2T_hi,
                                             const uint16_t* __restrict__ W2T_lo,
                                             const float* __restrict__ b1,
                                             const float* __restrict__ prelu_a,
                                             const float* __restrict__ b2,
                                             float* __restrict__ out) {
    __shared__ uint16_t hHi[32 * 136];
    __shared__ uint16_t hLo[32 * 136];
    __shared__ uint16_t h1Hi[32 * 136];
    __shared__ uint16_t h1Lo[32 * 136];
    int t = threadIdx.x;
    int nb = blockIdx.x * 32;

    // stage h rows -> bf16 hi/lo planes
    const float4* hb4 = (const float4*)(h_buf + (size_t)nb * 128);
    #pragma unroll
    for (int i = 0; i < 4; ++i) {
        int idx = i * 256 + t;             // float4 index, 1024 total
        int row = idx >> 5, c4 = idx & 31;
        float4 v = make_float4(0.f, 0.f, 0.f, 0.f);
        if (nb + row < N_NODES) v = hb4[idx];
        float xs[4] = {v.x, v.y, v.z, v.w};
        uint32_t hi[4], lo[4];
        #pragma unroll
        for (int j = 0; j < 4; ++j) {
            hi[j] = f2bf(xs[j]);
            lo[j] = f2bf(xs[j] - bflo(hi[j]));
        }
        uint32_t bo = row * 272 + c4 * 8;
        *(uint2*)((char*)hHi + bo) = make_uint2(hi[0] | (hi[1] << 16), hi[2] | (hi[3] << 16));
        *(uint2*)((char*)hLo + bo) = make_uint2(lo[0] | (lo[1] << 16), lo[2] | (lo[3] << 16));
    }
    __syncthreads();

    int w = t >> 6, l = t & 63;
    int lr = l & 15, lg = l >> 4;          // frag row/col lane, k-group
    // ---- layer 1: wave w -> col-tiles {2w, 2w+1}, both row-tiles ----
    float bb0 = b1[(2 * w) * 16 + lr];
    float bb1 = b1[(2 * w + 1) * 16 + lr];
    f32x4 acc[2][2];
    #pragma unroll
    for (int rt = 0; rt < 2; ++rt) {
        acc[rt][0] = (f32x4){bb0, bb0, bb0, bb0};
        acc[rt][1] = (f32x4){bb1, bb1, bb1, bb1};
    }
    #pragma unroll
    for (int s = 0; s < 4; ++s) {
        int koff = s * 64 + lg * 16;       // byte offset of k-chunk
        bf16x8 a_hi[2], a_lo[2], b_hi[2], b_lo[2];
        #pragma unroll
        for (int rt = 0; rt < 2; ++rt) {
            int ro = (rt * 16 + lr) * 272 + koff;
            a_hi[rt] = *(const bf16x8*)((const char*)hHi + ro);
            a_lo[rt] = *(const bf16x8*)((const char*)hLo + ro);
        }
        #pragma unroll
        for (int c = 0; c < 2; ++c) {
            int go = ((2 * w + c) * 16 + lr) * 256 + koff;
            b_hi[c] = *(const bf16x8*)((const char*)W1T_hi + go);
            b_lo[c] = *(const bf16x8*)((const char*)W1T_lo + go);
        }
        #pragma unroll
        for (int rt = 0; rt < 2; ++rt)
            #pragma unroll
            for (int c = 0; c < 2; ++c) {
                acc[rt][c] = __builtin_amdgcn_mfma_f32_16x16x32_bf16(a_hi[rt], b_hi[c], acc[rt][c], 0, 0, 0);
                acc[rt][c] = __builtin_amdgcn_mfma_f32_16x16x32_bf16(a_hi[rt], b_lo[c], acc[rt][c], 0, 0, 0);
                acc[rt][c] = __builtin_amdgcn_mfma_f32_16x16x32_bf16(a_lo[rt], b_hi[c], acc[rt][c], 0, 0, 0);
            }
    }
    // PReLU + re-split -> h1 planes
    float pa = prelu_a[0];
    #pragma unroll
    for (int rt = 0; rt < 2; ++rt)
        #pragma unroll
        for (int c = 0; c < 2; ++c) {
            int n = (2 * w + c) * 16 + lr;
            #pragma unroll
            for (int r = 0; r < 4; ++r) {
                float vv = acc[rt][c][r];
                vv = vv > 0.f ? vv : pa * vv;
                uint32_t hi = f2bf(vv);
                uint32_t lo = f2bf(vv - bflo(hi));
                int m = rt * 16 + lg * 4 + r;
                uint32_t bo = m * 272 + n * 2;
                *(uint16_t*)((char*)h1Hi + bo) = (uint16_t)hi;
                *(uint16_t*)((char*)h1Lo + bo) = (uint16_t)lo;
            }
        }
    __syncthreads();
    // ---- layer 2: wave w -> tile (rt = w&1, ct = w>>1) ----
    int rt2 = w & 1, ct2 = w >> 1;
    float bb2 = b2[ct2 * 16 + lr];
    f32x4 acc2 = (f32x4){bb2, bb2, bb2, bb2};
    #pragma unroll
    for (int s = 0; s < 4; ++s) {
        int koff = s * 64 + lg * 16;
        int ro = (rt2 * 16 + lr) * 272 + koff;
        bf16x8 a_hi = *(const bf16x8*)((const char*)h1Hi + ro);
        bf16x8 a_lo = *(const bf16x8*)((const char*)h1Lo + ro);
        int go = (ct2 * 16 + lr) * 256 + koff;
        bf16x8 w2h = *(const bf16x8*)((const char*)W2T_hi + go);
        bf16x8 w2l = *(const bf16x8*)((const char*)W2T_lo + go);
        acc2 = __builtin_amdgcn_mfma_f32_16x16x32_bf16(a_hi, w2h, acc2, 0, 0, 0);
        acc2 = __builtin_amdgcn_mfma_f32_16x16x32_bf16(a_hi, w2l, acc2, 0, 0, 0);
        acc2 = __builtin_amdgcn_mfma_f32_16x16x32_bf16(a_lo, w2h, acc2, 0, 0, 0);
    }
    #pragma unroll
    for (int r = 0; r < 4; ++r) {
        int m = rt2 * 16 + lg * 4 + r;
        if (nb + m < N_NODES)
            out[(size_t)(nb + m) * 32 + ct2 * 16 + lr] = acc2[r];
    }
}

// ---------------------------------------------------------------- launch

extern "C" void kernel_launch(void* const* d_in, const int* in_sizes, int n_in,
                              void* d_out, int out_size, void* d_ws, size_t ws_size,
                              hipStream_t stream) {
    const float* x        = (const float*)d_in[0];
    const int*   ei       = (const int*)d_in[1];     // int32 per harness contract
    const float* edge_attr= (const float*)d_in[2];
    const float* W_gat    = (const float*)d_in[3];
    const float* att_src  = (const float*)d_in[4];
    const float* att_dst  = (const float*)d_in[5];
    const float* W_edge   = (const float*)d_in[6];
    const float* att_edge = (const float*)d_in[7];
    const float* bias_gat = (const float*)d_in[8];
    const float* W1       = (const float*)d_in[9];
    const float* b1       = (const float*)d_in[10];
    const float* prelu_a  = (const float*)d_in[11];
    const float* W2       = (const float*)d_in[12];
    const float* b2       = (const float*)d_in[13];
    float*       out      = (float*)d_out;

    char* base = (char*)d_ws;
    size_t off = 0;
    auto alloc = [&](size_t bytes) -> void* {
        void* p = base + off;
        off = (off + bytes + 255) & ~(size_t)255;
        return p;
    };
    int*      bcur    = (int*)     alloc((size_t)NBUCK * 4);
    int*      bsum    = (int*)     alloc((size_t)NBUCK * 4);
    int*      bbase   = (int*)     alloc((size_t)(NBUCK + 1) * 4);
    float*    v       = (float*)   alloc(32 * 4);
    uint16_t* W1T_hi  = (uint16_t*)alloc((size_t)128 * 128 * 2);
    uint16_t* W1T_lo  = (uint16_t*)alloc((size_t)128 * 128 * 2);
    uint16_t* W2T_hi  = (uint16_t*)alloc((size_t)32 * 128 * 2);
    uint16_t* W2T_lo  = (uint16_t*)alloc((size_t)32 * 128 * 2);
    float*    a_src   = (float*)   alloc((size_t)N_NODES * 4 * 4);
    float*    a_dst   = (float*)   alloc((size_t)N_NODES * 4 * 4);
    float*    h_buf   = (float*)   alloc((size_t)N_NODES * 128 * 4);
    uint4*    stg     = (uint4*)   alloc((size_t)N_EDGES * 16);
    uint8_t*  stg8    = (uint8_t*) alloc((size_t)N_EDGES);

    k_zero196<<<1, 256, 0, stream>>>(bsum);
    k_bcnt  <<<NB_BC, 256, 0, stream>>>(ei, bsum);
    k_pre   <<<NB_PRE, 256, 0, stream>>>(x, W_gat, att_src, att_dst,
                                         W_edge, att_edge, W1, W2,
                                         (float4*)a_src, (float4*)a_dst, v,
                                         W1T_hi, W1T_lo, W2T_hi, W2T_lo);
    k_scanb <<<1, 256, 0, stream>>>(bsum, bbase, bcur);
    k_scat1 <<<P1_BLOCKS, P1_T, 0, stream>>>(
        ei, edge_attr, v, (const float4*)a_src, bcur, stg, stg8);
    k_scat2g<<<NBUCK, 1024, 0, stream>>>(
        bbase, stg, stg8, x, a_src, a_dst, W_gat, bias_gat, (float2*)h_buf);
    k_mlp   <<<(N_NODES + 31) / 32, 256, 0, stream>>>(
        h_buf, W1T_hi, W1T_lo, W2T_hi, W2T_lo, b1, prelu_a, b2, out);
}

// Round 12
// 225.530 us; speedup vs baseline: 1.2308x; 1.0143x over previous
//
#include <hip/hip_runtime.h>
#include <cstdint>

#define N_NODES 50000
#define N_EDGES 1600000
#define NH 4
#define CC 32
#define HC 128          // NH*CC
#define LAT 32
#define NEG_SLOPE 0.2f

// k_pre role split: [node | v | w1t | w2t]
#define NB_NODE 25                       // node: 2048 nodes per block
#define NB_PRE  (NB_NODE + 3)            // +v +w1t +w2t

// bucket count kernel
#define NB_BC   250                      // 250 x 6400-edge chunks
#define CH_E    6400

// bucketed scatter: bucket = dst >> 7 (128 nodes / bucket)
// halved from 256 so k_scat2g's LDS fits 2 blocks/CU (was 147KB -> 1 block,
// 16 waves/CU, the measured occupancy wall at 44us).
#define NBUCK 391                        // ceil(50000/128)
#define NPB   128                        // nodes per bucket
#define BSH   7
#define P1_T  512
#define P1_EPB (P1_T * 4)                // 2048 edges per phase-1 block
#define P1_BLOCKS ((N_EDGES + P1_EPB - 1) / P1_EPB)   // 782
#define CAP  4672                        // LDS bucket capacity (mean 4092 + 9 sigma)

typedef uint32_t u32x4 __attribute__((ext_vector_type(4)));
typedef __bf16   bf16x8 __attribute__((ext_vector_type(8)));
typedef float    f32x4 __attribute__((ext_vector_type(4)));

// ---------------- bf16 helpers (RNE pack, shift-unpack) ----------------
__device__ __forceinline__ float bflo(uint32_t u) {
    union { uint32_t i; float f; } c; c.i = u << 16; return c.f;
}
__device__ __forceinline__ float bfhi(uint32_t u) {
    union { uint32_t i; float f; } c; c.i = u & 0xFFFF0000u; return c.f;
}
__device__ __forceinline__ uint32_t f2bf(float f) {
    union { float f; uint32_t i; } c; c.f = f;
    return (c.i + 0x7FFFu + ((c.i >> 16) & 1u)) >> 16;
}
__device__ __forceinline__ uint32_t pack2(float a, float b) {
    return f2bf(a) | (f2bf(b) << 16);
}
__device__ __forceinline__ float bpermf(int byteIdx, float v) {
    return __int_as_float(__builtin_amdgcn_ds_bpermute(byteIdx, __float_as_int(v)));
}
// fp8 e4m3fn pack/unpack (ae only feeds the self-loop mean -> 6% rel err ok)
__device__ __forceinline__ uint32_t f2e4m3(float x) {
    uint32_t u = __float_as_uint(x);
    uint32_t s = u >> 31;
    uint32_t mag = u & 0x7fffffffu;
    mag += 0x7ffffu + ((mag >> 20) & 1u);       // RNE at bit 20
    uint32_t e = mag >> 23;
    if (e < 121u) return s << 7;                // underflow -> 0
    uint32_t code = ((e - 120u) << 3) | ((mag >> 20) & 7u);
    if (code > 0x7Eu) code = 0x7Eu;             // clamp to 448
    return (s << 7) | code;
}
__device__ __forceinline__ float e4m32f(uint32_t b) {
    uint32_t e = (b >> 3) & 15u;
    if (e == 0u) return 0.f;
    return __uint_as_float(((b >> 7) << 31) | ((e + 120u) << 23) | ((b & 7u) << 20));
}

// ---------------------------------------------------------------- kernels

// zero the 391 bucket counters (tiny)
__global__ __launch_bounds__(512) void k_zerob(int* __restrict__ bsum) {
    int t = threadIdx.x;
    if (t < NBUCK) bsum[t] = 0;
}

// bucket-size count: per-block 391-bin LDS histogram, then ONE global
// atomicAdd per (block,bin). Per-node degrees are derived locally by
// k_scat2g from its own slice (no global per-node counting at all).
__global__ __launch_bounds__(256) void k_bcnt(const int* __restrict__ ei,
                                              int* __restrict__ bsum) {
    __shared__ int bh[NBUCK];
    int t = threadIdx.x;
    for (int i = t; i < NBUCK; i += 256) bh[i] = 0;
    __syncthreads();
    int base = blockIdx.x * CH_E;
    #pragma unroll 1
    for (int it = 0; it < CH_E / 256; ++it) {
        int dst = ei[N_EDGES + base + it * 256 + t];
        atomicAdd(&bh[dst >> BSH], 1);
    }
    __syncthreads();
    for (int i = t; i < NBUCK; i += 256) {
        int h = bh[i];
        if (h) atomicAdd(&bsum[i], h);
    }
}

// front end: [node | v | w1t | w2t] by blockIdx range (28 blocks)
__global__ __launch_bounds__(256) void k_pre(const float* __restrict__ x,
                                             const float* __restrict__ W_gat,
                                             const float* __restrict__ att_src,
                                             const float* __restrict__ att_dst,
                                             const float* __restrict__ W_edge,
                                             const float* __restrict__ att_edge,
                                             const float* __restrict__ W1,
                                             const float* __restrict__ W2,
                                             float4* __restrict__ a_src,
                                             float4* __restrict__ a_dst,
                                             float* __restrict__ v,
                                             uint16_t* __restrict__ W1T_hi,
                                             uint16_t* __restrict__ W1T_lo,
                                             uint16_t* __restrict__ W2T_hi,
                                             uint16_t* __restrict__ W2T_lo) {
    int bid = blockIdx.x, t = threadIdx.x;
    if (bid < NB_NODE) {
        __shared__ float us[12], ud[12];
        if (t < 12) {
            int i = t >> 2, h = t & 3;
            float s = 0.f;
            #pragma unroll
            for (int c = 0; c < 32; ++c)
                s += W_gat[i * 128 + h * 32 + c] * att_src[h * 32 + c];
            us[t] = s;
        } else if (t < 24) {
            int q = t - 12; int i = q >> 2, h = q & 3;
            float s = 0.f;
            #pragma unroll
            for (int c = 0; c < 32; ++c)
                s += W_gat[i * 128 + h * 32 + c] * att_dst[h * 32 + c];
            ud[q] = s;
        }
        __syncthreads();
        int base = bid * 2048;
        #pragma unroll 1
        for (int i = 0; i < 8; ++i) {
            int n = base + i * 256 + t;
            if (n >= N_NODES) break;
            float x0 = x[n * 3 + 0], x1 = x[n * 3 + 1], x2 = x[n * 3 + 2];
            float s[4], d[4];
            #pragma unroll
            for (int h = 0; h < 4; ++h) {
                s[h] = x0 * us[h] + x1 * us[4 + h] + x2 * us[8 + h];
                d[h] = x0 * ud[h] + x1 * ud[4 + h] + x2 * ud[8 + h];
            }
            a_src[n] = make_float4(s[0], s[1], s[2], s[3]);
            a_dst[n] = make_float4(d[0], d[1], d[2], d[3]);
        }
    } else if (bid == NB_NODE) {
        if (t < 28) {
            int d = t >> 2, h = t & 3;
            float s = 0.f;
            #pragma unroll
            for (int c = 0; c < 32; ++c)
                s += W_edge[d * 128 + h * 32 + c] * att_edge[h * 32 + c];
            v[t] = s;
        }
    } else if (bid == NB_NODE + 1) {
        // W1T bf16 hi/lo planes: W1T[n][k] = W1[k][n]
        #pragma unroll 4
        for (int i = 0; i < 64; ++i) {
            int idx = i * 256 + t;             // 16384
            int n = idx >> 7, k = idx & 127;
            float vv = W1[k * 128 + n];
            uint32_t hi = f2bf(vv);
            uint32_t lo = f2bf(vv - bflo(hi));
            W1T_hi[idx] = (uint16_t)hi;
            W1T_lo[idx] = (uint16_t)lo;
        }
    } else {
        // W2T bf16 hi/lo planes: W2T[j][k] = W2[k][j]
        #pragma unroll 4
        for (int i = 0; i < 16; ++i) {
            int idx = i * 256 + t;             // 4096
            int j = idx >> 7, k = idx & 127;
            float vv = W2[k * 32 + j];
            uint32_t hi = f2bf(vv);
            uint32_t lo = f2bf(vv - bflo(hi));
            W2T_hi[idx] = (uint16_t)hi;
            W2T_lo[idx] = (uint16_t)lo;
        }
    }
}

// single block: exclusive scan of 391 bucket sums -> bbase[0..391], bcur
__global__ __launch_bounds__(512) void k_scanb(const int* __restrict__ bsum,
                                               int* __restrict__ bbase,
                                               int* __restrict__ bcur) {
    __shared__ int sh[512];
    int t = threadIdx.x;
    int vv = (t < NBUCK) ? bsum[t] : 0;
    sh[t] = vv;
    __syncthreads();
    #pragma unroll
    for (int off = 1; off < 512; off <<= 1) {
        int xv = (t >= off) ? sh[t - off] : 0;
        __syncthreads();
        sh[t] += xv;
        __syncthreads();
    }
    if (t < NBUCK) { bbase[t] = sh[t] - vv; bcur[t] = sh[t] - vv; }
    if (t == 511) bbase[NBUCK] = sh[511];      // grand total (= N_EDGES)
}

// scatter: compute records (comb = ae + a_src, 4xfp8 ae in pad word,
// dst&127 in bits 16..23 of the src word), stage bucket-partitioned.
// LDS-bucket-sorted copy-out + 1-byte dst sidecar (stg8) so the fused
// gather can count per-node degrees with a cheap coalesced byte pass.
__global__ __launch_bounds__(512) void k_scat1(const int* __restrict__ ei,
                                               const float* __restrict__ edge_attr,
                                               const float* __restrict__ v,
                                               const float4* __restrict__ a_src,
                                               int* __restrict__ bcur,
                                               uint4* __restrict__ stg,
                                               uint8_t* __restrict__ stg8) {
    __shared__ int bh[NBUCK];        // per-block bucket histogram
    __shared__ int bg[NBUCK];        // this block's global base per bucket
    __shared__ int bl[NBUCK];        // local cursor per bucket
    __shared__ int bo[NBUCK];        // block-local exclusive offset per bucket
    __shared__ int sct[512];         // scan temp
    __shared__ u32x4 lrec[P1_EPB];   // bucket-sorted records (32KB)
    __shared__ int gaddr[P1_EPB];    // global slot per record (8KB)
    int t = threadIdx.x;
    float vsr[28];
    #pragma unroll
    for (int i = 0; i < 28; ++i) vsr[i] = v[i];   // uniform addr -> s_load

    for (int i = t; i < NBUCK; i += P1_T) bh[i] = 0;
    __syncthreads();

    int e0 = blockIdx.x * P1_EPB + t * 4;          // 4 consecutive edges
    bool act = (e0 < N_EDGES);                     // tail is a multiple of 4
    int dst[4];
    uint4 rec[4];
    if (act) {
        int4 s4 = *(const int4*)&ei[e0];
        int4 d4 = *(const int4*)&ei[N_EDGES + e0];
        int srcv[4] = {s4.x, s4.y, s4.z, s4.w};
        dst[0] = d4.x; dst[1] = d4.y; dst[2] = d4.z; dst[3] = d4.w;

        float4 as4[4];
        #pragma unroll
        for (int q = 0; q < 4; ++q)
            as4[q] = a_src[srcv[q]];               // L2-resident 800KB table

        const float4* ea4 = (const float4*)&edge_attr[e0 * 7];
        float ea[28];
        #pragma unroll
        for (int i = 0; i < 7; ++i) {
            float4 vv = ea4[i];
            ea[i * 4 + 0] = vv.x; ea[i * 4 + 1] = vv.y;
            ea[i * 4 + 2] = vv.z; ea[i * 4 + 3] = vv.w;
        }

        #pragma unroll
        for (int q = 0; q < 4; ++q) {
            float asv[4] = {as4[q].x, as4[q].y, as4[q].z, as4[q].w};
            float comb[4];
            uint32_t ae8 = 0;
            #pragma unroll
            for (int h = 0; h < 4; ++h) {
                float aeh = 0.f;
                #pragma unroll
                for (int d = 0; d < 7; ++d) aeh += ea[q * 7 + d] * vsr[d * 4 + h];
                ae8 |= f2e4m3(aeh) << (h * 8);
                comb[h] = aeh + asv[h];
            }
            rec[q] = make_uint4(pack2(comb[0], comb[1]), pack2(comb[2], comb[3]),
                                (uint32_t)srcv[q] | ((uint32_t)(dst[q] & (NPB - 1)) << 16),
                                ae8);
            atomicAdd(&bh[dst[q] >> BSH], 1);
        }
    }
    __syncthreads();
    // block-local exclusive scan of bh (391 -> 512-wide Hillis-Steele)
    int hv = (t < NBUCK) ? bh[t] : 0;
    sct[t] = hv;
    __syncthreads();
    #pragma unroll
    for (int off = 1; off < 512; off <<= 1) {
        int xv = (t >= off) ? sct[t - off] : 0;
        __syncthreads();
        sct[t] += xv;
        __syncthreads();
    }
    if (t < NBUCK) {
        bo[t] = sct[t] - hv;                       // local exclusive base
        bg[t] = hv ? atomicAdd(&bcur[t], hv) : 0;  // global run base
        bl[t] = 0;
    }
    __syncthreads();
    if (act) {
        #pragma unroll
        for (int q = 0; q < 4; ++q) {
            int bk = dst[q] >> BSH;
            int off = atomicAdd(&bl[bk], 1);       // fast LDS cursor
            int slot = bo[bk] + off;
            lrec[slot] = (u32x4){rec[q].x, rec[q].y, rec[q].z, rec[q].w};
            gaddr[slot] = bg[bk] + off;
        }
    }
    __syncthreads();
    int total = sct[511];                          // records in this block
    for (int s = t; s < total; s += P1_T) {
        u32x4 r = lrec[s];
        int ga = gaddr[s];
        stg[ga] = make_uint4(r.x, r.y, r.z, r.w);
        stg8[ga] = (uint8_t)(r.z >> 16);
    }
}

// fused sort+gather: one 1024-thread block per 128-node bucket (75KB LDS ->
// 2 blocks/CU = full 32-wave occupancy, vs 256-node/147KB/1-block before).
// phase 0: per-node degrees from the 1-byte sidecar + 128-wide local scan
// phase 1: node-sort the ~4092 records into LDS (one ds atomicSub each)
// phase 2: per-wave node gather straight from LDS (k_gather v3 math).
__global__ __launch_bounds__(1024) void k_scat2g(const int* __restrict__ bbase,
                                                 const uint4* __restrict__ stg,
                                                 const uint8_t* __restrict__ stg8,
                                                 const float* __restrict__ x,
                                                 const float* __restrict__ a_src,
                                                 const float* __restrict__ a_dst,
                                                 const float* __restrict__ W_gat,
                                                 const float* __restrict__ bias_gat,
                                                 float2* __restrict__ h_buf) {
    __shared__ int rp[NPB + 1];
    __shared__ int lcnt[NPB];
    __shared__ int dcnt[NPB];
    __shared__ u32x4 lrec[CAP];      // 74.8KB bucket-local CSR
    int b = blockIdx.x, t = threadIdx.x;
    int n0 = b << BSH;
    int nn = min(NPB, N_NODES - n0);
    int base = bbase[b];
    int total = bbase[b + 1] - base;
    if (t < NPB) dcnt[t] = 0;
    __syncthreads();

    // phase 0: degree count from sidecar
    for (int e = t; e < total; e += 1024)
        atomicAdd(&dcnt[(int)stg8[base + e]], 1);
    __syncthreads();
    // 128-wide inclusive scan -> exclusive rp[0..128]
    if (t < NPB) rp[t] = dcnt[t];
    __syncthreads();
    #pragma unroll
    for (int off = 1; off < NPB; off <<= 1) {
        int xv = 0;
        if (t < NPB && t >= off) xv = rp[t - off];
        __syncthreads();
        if (t < NPB) rp[t] += xv;
        __syncthreads();
    }
    int incl = (t < NPB) ? rp[t] : 0;
    __syncthreads();
    if (t < NPB) {
        rp[t + 1] = incl;              // rp[1..128] = inclusive prefix
        if (t == 0) rp[0] = 0;
        lcnt[t] = dcnt[t];
    }
    __syncthreads();

    // phase 1: node-sort the stg slice into LDS (coalesced read)
    for (int e = t; e < total; e += 1024) {
        uint4 r = stg[base + e];
        int dl = (int)((r.z >> 16) & 0xFFu);
        int c = atomicSub(&lcnt[dl], 1);
        int slot = rp[dl] + c - 1;
        if (slot < CAP) lrec[slot] = (u32x4){r.x, r.y, r.z, r.w};
    }
    __syncthreads();

    // phase 2: wave wv gathers nodes wv*8 .. wv*8+7 from LDS
    int wv = t >> 6, l = t & 63;
    int h = l & 3;                 // aggregation head
    int slot = l >> 2;             // edge slot 0..15
    int c0 = 2 * l;
    float w00 = W_gat[c0],       w01 = W_gat[c0 + 1];
    float w10 = W_gat[128 + c0], w11 = W_gat[128 + c0 + 1];
    float w20 = W_gat[256 + c0], w21 = W_gat[256 + c0 + 1];
    float2 bia = ((const float2*)bias_gat)[l];

    #pragma unroll 1
    for (int j = 0; j < 8; ++j) {
        int i = wv * 8 + j;
        if (i >= nn) break;                        // wave-uniform
        int n = n0 + i;
        int start = rp[i], end = rp[i + 1];
        int deg = end - start;
        float ad_n = a_dst[n * 4 + h];
        float as_n = a_src[n * 4 + h];
        float sx0 = 0.f, sx1 = 0.f, sx2 = 0.f, den = 0.f, aes = 0.f;

        for (int p0 = start; p0 < end; p0 += 16) {
            int e = p0 + slot;
            float w = 0.f, ae = 0.f;
            int src = n;
            if (e < end) {
                u32x4 rc = lrec[e];
                uint32_t aw = (h < 2) ? rc.x : rc.y;
                float comb = (h & 1) ? bfhi(aw) : bflo(aw);   // ae + a_src[src]
                ae = e4m32f((rc.w >> (h * 8)) & 0xffu);
                src = (int)(rc.z & 0xFFFFu);
                float al = comb + ad_n;
                al = al > 0.f ? al : NEG_SLOPE * al;
                w = __expf(al);
            }
            const float* xr = x + src * 3;                    // L2-hot table
            sx0 += w * xr[0];
            sx1 += w * xr[1];
            sx2 += w * xr[2];
            den += w;
            aes += ae;
        }

        // allreduce across the 16 slots (lanes with equal l&3)
        #pragma unroll
        for (int m = 4; m <= 32; m <<= 1) {
            sx0 += __shfl_xor(sx0, m);
            sx1 += __shfl_xor(sx1, m);
            sx2 += __shfl_xor(sx2, m);
            den += __shfl_xor(den, m);
            aes += __shfl_xor(aes, m);
        }

        // self loop: edge_attr = mean of incoming aeh
        float xn0 = x[n * 3], xn1 = x[n * 3 + 1], xn2 = x[n * 3 + 2];
        float invd = (deg > 0) ? (1.0f / (float)deg) : 1.0f;
        float alS = as_n + ad_n + aes * invd;
        alS = alS > 0.f ? alS : NEG_SLOPE * alS;
        float wS = __expf(alS);
        sx0 += wS * xn0; sx1 += wS * xn1; sx2 += wS * xn2;
        den += wS;

        // lane l needs head l>>4 totals (all lanes hold their head's total)
        int sb = (l >> 4) << 2;
        float t0 = bpermf(sb, sx0);
        float t1 = bpermf(sb, sx1);
        float t2 = bpermf(sb, sx2);
        float td = bpermf(sb, den);

        float r = 1.0f / td;
        float o0 = (t0 * w00 + t1 * w10 + t2 * w20) * r + bia.x;
        float o1 = (t0 * w01 + t1 * w11 + t2 * w21) * r + bia.y;
        o0 = o0 > 0.f ? o0 : (__expf(o0) - 1.0f);   // ELU
        o1 = o1 > 0.f ? o1 : (__expf(o1) - 1.0f);
        h_buf[(size_t)n * 64 + l] = make_float2(o0, o1);
    }
}

// MFMA MLP: 32 rows/block, 4 waves. bf16 hi/lo split (3-term) for ~fp32
// accuracy at matrix-pipe rate. LDS planes [32][136] bf16 (row stride 272B).
__global__ __launch_bounds__(256) void k_mlp(const float* __restrict__ h_buf,
                                             const uint16_t* __restrict__ W1T_hi,
                                             const uint16_t* __restrict__ W1T_lo,
                                             const uint16_t* __restrict__ W2T_hi,
                                             const uint16_t* __restrict__ W2T_lo,
                                             const float* __restrict__ b1,
                                             const float* __restrict__ prelu_a,
                                             const float* __restrict__ b2,
                                             float* __restrict__ out) {
    __shared__ uint16_t hHi[32 * 136];
    __shared__ uint16_t hLo[32 * 136];
    __shared__ uint16_t h1Hi[32 * 136];
    __shared__ uint16_t h1Lo[32 * 136];
    int t = threadIdx.x;
    int nb = blockIdx.x * 32;

    // stage h rows -> bf16 hi/lo planes
    const float4* hb4 = (const float4*)(h_buf + (size_t)nb * 128);
    #pragma unroll
    for (int i = 0; i < 4; ++i) {
        int idx = i * 256 + t;             // float4 index, 1024 total
        int row = idx >> 5, c4 = idx & 31;
        float4 v = make_float4(0.f, 0.f, 0.f, 0.f);
        if (nb + row < N_NODES) v = hb4[idx];
        float xs[4] = {v.x, v.y, v.z, v.w};
        uint32_t hi[4], lo[4];
        #pragma unroll
        for (int j = 0; j < 4; ++j) {
            hi[j] = f2bf(xs[j]);
            lo[j] = f2bf(xs[j] - bflo(hi[j]));
        }
        uint32_t bo = row * 272 + c4 * 8;
        *(uint2*)((char*)hHi + bo) = make_uint2(hi[0] | (hi[1] << 16), hi[2] | (hi[3] << 16));
        *(uint2*)((char*)hLo + bo) = make_uint2(lo[0] | (lo[1] << 16), lo[2] | (lo[3] << 16));
    }
    __syncthreads();

    int w = t >> 6, l = t & 63;
    int lr = l & 15, lg = l >> 4;          // frag row/col lane, k-group
    // ---- layer 1: wave w -> col-tiles {2w, 2w+1}, both row-tiles ----
    float bb0 = b1[(2 * w) * 16 + lr];
    float bb1 = b1[(2 * w + 1) * 16 + lr];
    f32x4 acc[2][2];
    #pragma unroll
    for (int rt = 0; rt < 2; ++rt) {
        acc[rt][0] = (f32x4){bb0, bb0, bb0, bb0};
        acc[rt][1] = (f32x4){bb1, bb1, bb1, bb1};
    }
    #pragma unroll
    for (int s = 0; s < 4; ++s) {
        int koff = s * 64 + lg * 16;       // byte offset of k-chunk
        bf16x8 a_hi[2], a_lo[2], b_hi[2], b_lo[2];
        #pragma unroll
        for (int rt = 0; rt < 2; ++rt) {
            int ro = (rt * 16 + lr) * 272 + koff;
            a_hi[rt] = *(const bf16x8*)((const char*)hHi + ro);
            a_lo[rt] = *(const bf16x8*)((const char*)hLo + ro);
        }
        #pragma unroll
        for (int c = 0; c < 2; ++c) {
            int go = ((2 * w + c) * 16 + lr) * 256 + koff;
            b_hi[c] = *(const bf16x8*)((const char*)W1T_hi + go);
            b_lo[c] = *(const bf16x8*)((const char*)W1T_lo + go);
        }
        #pragma unroll
        for (int rt = 0; rt < 2; ++rt)
            #pragma unroll
            for (int c = 0; c < 2; ++c) {
                acc[rt][c] = __builtin_amdgcn_mfma_f32_16x16x32_bf16(a_hi[rt], b_hi[c], acc[rt][c], 0, 0, 0);
                acc[rt][c] = __builtin_amdgcn_mfma_f32_16x16x32_bf16(a_hi[rt], b_lo[c], acc[rt][c], 0, 0, 0);
                acc[rt][c] = __builtin_amdgcn_mfma_f32_16x16x32_bf16(a_lo[rt], b_hi[c], acc[rt][c], 0, 0, 0);
            }
    }
    // PReLU + re-split -> h1 planes
    float pa = prelu_a[0];
    #pragma unroll
    for (int rt = 0; rt < 2; ++rt)
        #pragma unroll
        for (int c = 0; c < 2; ++c) {
            int n = (2 * w + c) * 16 + lr;
            #pragma unroll
            for (int r = 0; r < 4; ++r) {
                float vv = acc[rt][c][r];
                vv = vv > 0.f ? vv : pa * vv;
                uint32_t hi = f2bf(vv);
                uint32_t lo = f2bf(vv - bflo(hi));
                int m = rt * 16 + lg * 4 + r;
                uint32_t bo = m * 272 + n * 2;
                *(uint16_t*)((char*)h1Hi + bo) = (uint16_t)hi;
                *(uint16_t*)((char*)h1Lo + bo) = (uint16_t)lo;
            }
        }
    __syncthreads();
    // ---- layer 2: wave w -> tile (rt = w&1, ct = w>>1) ----
    int rt2 = w & 1, ct2 = w >> 1;
    float bb2 = b2[ct2 * 16 + lr];
    f32x4 acc2 = (f32x4){bb2, bb2, bb2, bb2};
    #pragma unroll
    for (int s = 0; s < 4; ++s) {
        int koff = s * 64 + lg * 16;
        int ro = (rt2 * 16 + lr) * 272 + koff;
        bf16x8 a_hi = *(const bf16x8*)((const char*)h1Hi + ro);
        bf16x8 a_lo = *(const bf16x8*)((const char*)h1Lo + ro);
        int go = (ct2 * 16 + lr) * 256 + koff;
        bf16x8 w2h = *(const bf16x8*)((const char*)W2T_hi + go);
        bf16x8 w2l = *(const bf16x8*)((const char*)W2T_lo + go);
        acc2 = __builtin_amdgcn_mfma_f32_16x16x32_bf16(a_hi, w2h, acc2, 0, 0, 0);
        acc2 = __builtin_amdgcn_mfma_f32_16x16x32_bf16(a_hi, w2l, acc2, 0, 0, 0);
        acc2 = __builtin_amdgcn_mfma_f32_16x16x32_bf16(a_lo, w2h, acc2, 0, 0, 0);
    }
    #pragma unroll
    for (int r = 0; r < 4; ++r) {
        int m = rt2 * 16 + lg * 4 + r;
        if (nb + m < N_NODES)
            out[(size_t)(nb + m) * 32 + ct2 * 16 + lr] = acc2[r];
    }
}

// ---------------------------------------------------------------- launch

extern "C" void kernel_launch(void* const* d_in, const int* in_sizes, int n_in,
                              void* d_out, int out_size, void* d_ws, size_t ws_size,
                              hipStream_t stream) {
    const float* x        = (const float*)d_in[0];
    const int*   ei       = (const int*)d_in[1];     // int32 per harness contract
    const float* edge_attr= (const float*)d_in[2];
    const float* W_gat    = (const float*)d_in[3];
    const float* att_src  = (const float*)d_in[4];
    const float* att_dst  = (const float*)d_in[5];
    const float* W_edge   = (const float*)d_in[6];
    const float* att_edge = (const float*)d_in[7];
    const float* bias_gat = (const float*)d_in[8];
    const float* W1       = (const float*)d_in[9];
    const float* b1       = (const float*)d_in[10];
    const float* prelu_a  = (const float*)d_in[11];
    const float* W2       = (const float*)d_in[12];
    const float* b2       = (const float*)d_in[13];
    float*       out      = (float*)d_out;

    char* base = (char*)d_ws;
    size_t off = 0;
    auto alloc = [&](size_t bytes) -> void* {
        void* p = base + off;
        off = (off + bytes + 255) & ~(size_t)255;
        return p;
    };
    int*      bcur    = (int*)     alloc((size_t)NBUCK * 4);
    int*      bsum    = (int*)     alloc((size_t)NBUCK * 4);
    int*      bbase   = (int*)     alloc((size_t)(NBUCK + 1) * 4);
    float*    v       = (float*)   alloc(32 * 4);
    uint16_t* W1T_hi  = (uint16_t*)alloc((size_t)128 * 128 * 2);
    uint16_t* W1T_lo  = (uint16_t*)alloc((size_t)128 * 128 * 2);
    uint16_t* W2T_hi  = (uint16_t*)alloc((size_t)32 * 128 * 2);
    uint16_t* W2T_lo  = (uint16_t*)alloc((size_t)32 * 128 * 2);
    float*    a_src   = (float*)   alloc((size_t)N_NODES * 4 * 4);
    float*    a_dst   = (float*)   alloc((size_t)N_NODES * 4 * 4);
    float*    h_buf   = (float*)   alloc((size_t)N_NODES * 128 * 4);
    uint4*    stg     = (uint4*)   alloc((size_t)N_EDGES * 16);
    uint8_t*  stg8    = (uint8_t*) alloc((size_t)N_EDGES);

    k_zerob <<<1, 512, 0, stream>>>(bsum);
    k_bcnt  <<<NB_BC, 256, 0, stream>>>(ei, bsum);
    k_pre   <<<NB_PRE, 256, 0, stream>>>(x, W_gat, att_src, att_dst,
                                         W_edge, att_edge, W1, W2,
                                         (float4*)a_src, (float4*)a_dst, v,
                                         W1T_hi, W1T_lo, W2T_hi, W2T_lo);
    k_scanb <<<1, 512, 0, stream>>>(bsum, bbase, bcur);
    k_scat1 <<<P1_BLOCKS, P1_T, 0, stream>>>(
        ei, edge_attr, v, (const float4*)a_src, bcur, stg, stg8);
    k_scat2g<<<NBUCK, 1024, 0, stream>>>(
        bbase, stg, stg8, x, a_src, a_dst, W_gat, bias_gat, (float2*)h_buf);
    k_mlp   <<<(N_NODES + 31) / 32, 256, 0, stream>>>(
        h_buf, W1T_hi, W1T_lo, W2T_hi, W2T_lo, b1, prelu_a, b2, out);
}

// Round 13
// 214.365 us; speedup vs baseline: 1.2949x; 1.0521x over previous
//
#include <hip/hip_runtime.h>
#include <cstdint>

#define N_NODES 50000
#define N_EDGES 1600000
#define NH 4
#define CC 32
#define HC 128          // NH*CC
#define LAT 32
#define NEG_SLOPE 0.2f

// fused k_pre role split: [bcnt | node | v | w1t | w2t]
#define NB_BC   250                      // 250 x 6400-edge bucket-count chunks
#define CH_E    6400
#define NB_NODE 25                       // node: 2048 nodes per block
#define NB_PRE  (NB_BC + NB_NODE + 3)    // +v +w1t +w2t

// bucketed scatter: bucket = dst >> 7 (128 nodes / bucket)
#define NBUCK 391                        // ceil(50000/128)
#define NPB   128                        // nodes per bucket
#define BSH   7
#define P1_T  512
#define P1_EPB (P1_T * 4)                // 2048 edges per phase-1 block
#define P1_BLOCKS ((N_EDGES + P1_EPB - 1) / P1_EPB)   // 782
#define CAP  4672                        // LDS bucket capacity (mean 4092 + 9 sigma)

typedef uint32_t u32x4 __attribute__((ext_vector_type(4)));
typedef __bf16   bf16x8 __attribute__((ext_vector_type(8)));
typedef float    f32x4 __attribute__((ext_vector_type(4)));

// ---------------- bf16 helpers (RNE pack, shift-unpack) ----------------
__device__ __forceinline__ float bflo(uint32_t u) {
    union { uint32_t i; float f; } c; c.i = u << 16; return c.f;
}
__device__ __forceinline__ float bfhi(uint32_t u) {
    union { uint32_t i; float f; } c; c.i = u & 0xFFFF0000u; return c.f;
}
__device__ __forceinline__ uint32_t f2bf(float f) {
    union { float f; uint32_t i; } c; c.f = f;
    return (c.i + 0x7FFFu + ((c.i >> 16) & 1u)) >> 16;
}
__device__ __forceinline__ uint32_t pack2(float a, float b) {
    return f2bf(a) | (f2bf(b) << 16);
}
__device__ __forceinline__ float bpermf(int byteIdx, float v) {
    return __int_as_float(__builtin_amdgcn_ds_bpermute(byteIdx, __float_as_int(v)));
}
// fp8 e4m3fn pack/unpack (ae only feeds the self-loop mean -> 6% rel err ok)
__device__ __forceinline__ uint32_t f2e4m3(float x) {
    uint32_t u = __float_as_uint(x);
    uint32_t s = u >> 31;
    uint32_t mag = u & 0x7fffffffu;
    mag += 0x7ffffu + ((mag >> 20) & 1u);       // RNE at bit 20
    uint32_t e = mag >> 23;
    if (e < 121u) return s << 7;                // underflow -> 0
    uint32_t code = ((e - 120u) << 3) | ((mag >> 20) & 7u);
    if (code > 0x7Eu) code = 0x7Eu;             // clamp to 448
    return (s << 7) | code;
}
__device__ __forceinline__ float e4m32f(uint32_t b) {
    uint32_t e = (b >> 3) & 15u;
    if (e == 0u) return 0.f;
    return __uint_as_float(((b >> 7) << 31) | ((e + 120u) << 23) | ((b & 7u) << 20));
}

// ---------------------------------------------------------------- kernels

// zero the 391 bucket counters (tiny)
__global__ __launch_bounds__(512) void k_zerob(int* __restrict__ bsum) {
    int t = threadIdx.x;
    if (t < NBUCK) bsum[t] = 0;
}

// fused front end: [bcnt | node | v | w1t | w2t] by blockIdx range.
// bcnt role: per-block 391-bin LDS histogram, then ONE global atomicAdd
// per (block,bin). Per-node degrees are derived locally by k_scat2g.
__global__ __launch_bounds__(256) void k_pre(const float* __restrict__ x,
                                             const int* __restrict__ ei,
                                             const float* __restrict__ W_gat,
                                             const float* __restrict__ att_src,
                                             const float* __restrict__ att_dst,
                                             const float* __restrict__ W_edge,
                                             const float* __restrict__ att_edge,
                                             const float* __restrict__ W1,
                                             const float* __restrict__ W2,
                                             int* __restrict__ bsum,
                                             float4* __restrict__ a_src,
                                             float4* __restrict__ a_dst,
                                             float* __restrict__ v,
                                             uint16_t* __restrict__ W1T_hi,
                                             uint16_t* __restrict__ W1T_lo,
                                             uint16_t* __restrict__ W2T_hi,
                                             uint16_t* __restrict__ W2T_lo) {
    __shared__ int bh[NBUCK];
    int bid = blockIdx.x, t = threadIdx.x;
    if (bid < NB_BC) {
        for (int i = t; i < NBUCK; i += 256) bh[i] = 0;
        __syncthreads();
        int base = bid * CH_E;
        #pragma unroll 1
        for (int it = 0; it < CH_E / 256; ++it) {
            int dst = ei[N_EDGES + base + it * 256 + t];
            atomicAdd(&bh[dst >> BSH], 1);
        }
        __syncthreads();
        for (int i = t; i < NBUCK; i += 256) {
            int h = bh[i];
            if (h) atomicAdd(&bsum[i], h);
        }
    } else if (bid < NB_BC + NB_NODE) {
        __shared__ float us[12], ud[12];
        if (t < 12) {
            int i = t >> 2, h = t & 3;
            float s = 0.f;
            #pragma unroll
            for (int c = 0; c < 32; ++c)
                s += W_gat[i * 128 + h * 32 + c] * att_src[h * 32 + c];
            us[t] = s;
        } else if (t < 24) {
            int q = t - 12; int i = q >> 2, h = q & 3;
            float s = 0.f;
            #pragma unroll
            for (int c = 0; c < 32; ++c)
                s += W_gat[i * 128 + h * 32 + c] * att_dst[h * 32 + c];
            ud[q] = s;
        }
        __syncthreads();
        int base = (bid - NB_BC) * 2048;
        #pragma unroll 1
        for (int i = 0; i < 8; ++i) {
            int n = base + i * 256 + t;
            if (n >= N_NODES) break;
            float x0 = x[n * 3 + 0], x1 = x[n * 3 + 1], x2 = x[n * 3 + 2];
            float s[4], d[4];
            #pragma unroll
            for (int h = 0; h < 4; ++h) {
                s[h] = x0 * us[h] + x1 * us[4 + h] + x2 * us[8 + h];
                d[h] = x0 * ud[h] + x1 * ud[4 + h] + x2 * ud[8 + h];
            }
            a_src[n] = make_float4(s[0], s[1], s[2], s[3]);
            a_dst[n] = make_float4(d[0], d[1], d[2], d[3]);
        }
    } else if (bid == NB_BC + NB_NODE) {
        if (t < 28) {
            int d = t >> 2, h = t & 3;
            float s = 0.f;
            #pragma unroll
            for (int c = 0; c < 32; ++c)
                s += W_edge[d * 128 + h * 32 + c] * att_edge[h * 32 + c];
            v[t] = s;
        }
    } else if (bid == NB_BC + NB_NODE + 1) {
        // W1T bf16 hi/lo planes: W1T[n][k] = W1[k][n]
        #pragma unroll 4
        for (int i = 0; i < 64; ++i) {
            int idx = i * 256 + t;             // 16384
            int n = idx >> 7, k = idx & 127;
            float vv = W1[k * 128 + n];
            uint32_t hi = f2bf(vv);
            uint32_t lo = f2bf(vv - bflo(hi));
            W1T_hi[idx] = (uint16_t)hi;
            W1T_lo[idx] = (uint16_t)lo;
        }
    } else {
        // W2T bf16 hi/lo planes: W2T[j][k] = W2[k][j]
        #pragma unroll 4
        for (int i = 0; i < 16; ++i) {
            int idx = i * 256 + t;             // 4096
            int j = idx >> 7, k = idx & 127;
            float vv = W2[k * 32 + j];
            uint32_t hi = f2bf(vv);
            uint32_t lo = f2bf(vv - bflo(hi));
            W2T_hi[idx] = (uint16_t)hi;
            W2T_lo[idx] = (uint16_t)lo;
        }
    }
}

// single block: exclusive scan of 391 bucket sums -> bbase[0..391], bcur
__global__ __launch_bounds__(512) void k_scanb(const int* __restrict__ bsum,
                                               int* __restrict__ bbase,
                                               int* __restrict__ bcur) {
    __shared__ int sh[512];
    int t = threadIdx.x;
    int vv = (t < NBUCK) ? bsum[t] : 0;
    sh[t] = vv;
    __syncthreads();
    #pragma unroll
    for (int off = 1; off < 512; off <<= 1) {
        int xv = (t >= off) ? sh[t - off] : 0;
        __syncthreads();
        sh[t] += xv;
        __syncthreads();
    }
    if (t < NBUCK) { bbase[t] = sh[t] - vv; bcur[t] = sh[t] - vv; }
    if (t == 511) bbase[NBUCK] = sh[511];      // grand total (= N_EDGES)
}

// scatter: compute records (comb = ae + a_src, 4xfp8 ae in pad word,
// dst&127 in bits 16..23 of the src word), stage bucket-partitioned.
// LDS-bucket-sorted copy-out. NO byte sidecar: round-12 counters showed
// the 1.6MB stg8 byte-scatter cost ~11MB of amplified write traffic;
// k_scat2g reads the dst byte from the records directly instead.
__global__ __launch_bounds__(512) void k_scat1(const int* __restrict__ ei,
                                               const float* __restrict__ edge_attr,
                                               const float* __restrict__ v,
                                               const float4* __restrict__ a_src,
                                               int* __restrict__ bcur,
                                               uint4* __restrict__ stg) {
    __shared__ int bh[NBUCK];        // per-block bucket histogram
    __shared__ int bg[NBUCK];        // this block's global base per bucket
    __shared__ int bl[NBUCK];        // local cursor per bucket
    __shared__ int bo[NBUCK];        // block-local exclusive offset per bucket
    __shared__ int sct[512];         // scan temp
    __shared__ u32x4 lrec[P1_EPB];   // bucket-sorted records (32KB)
    __shared__ int gaddr[P1_EPB];    // global slot per record (8KB)
    int t = threadIdx.x;
    float vsr[28];
    #pragma unroll
    for (int i = 0; i < 28; ++i) vsr[i] = v[i];   // uniform addr -> s_load

    for (int i = t; i < NBUCK; i += P1_T) bh[i] = 0;
    __syncthreads();

    int e0 = blockIdx.x * P1_EPB + t * 4;          // 4 consecutive edges
    bool act = (e0 < N_EDGES);                     // tail is a multiple of 4
    int dst[4];
    uint4 rec[4];
    if (act) {
        int4 s4 = *(const int4*)&ei[e0];
        int4 d4 = *(const int4*)&ei[N_EDGES + e0];
        int srcv[4] = {s4.x, s4.y, s4.z, s4.w};
        dst[0] = d4.x; dst[1] = d4.y; dst[2] = d4.z; dst[3] = d4.w;

        float4 as4[4];
        #pragma unroll
        for (int q = 0; q < 4; ++q)
            as4[q] = a_src[srcv[q]];               // L2-resident 800KB table

        const float4* ea4 = (const float4*)&edge_attr[e0 * 7];
        float ea[28];
        #pragma unroll
        for (int i = 0; i < 7; ++i) {
            float4 vv = ea4[i];
            ea[i * 4 + 0] = vv.x; ea[i * 4 + 1] = vv.y;
            ea[i * 4 + 2] = vv.z; ea[i * 4 + 3] = vv.w;
        }

        #pragma unroll
        for (int q = 0; q < 4; ++q) {
            float asv[4] = {as4[q].x, as4[q].y, as4[q].z, as4[q].w};
            float comb[4];
            uint32_t ae8 = 0;
            #pragma unroll
            for (int h = 0; h < 4; ++h) {
                float aeh = 0.f;
                #pragma unroll
                for (int d = 0; d < 7; ++d) aeh += ea[q * 7 + d] * vsr[d * 4 + h];
                ae8 |= f2e4m3(aeh) << (h * 8);
                comb[h] = aeh + asv[h];
            }
            rec[q] = make_uint4(pack2(comb[0], comb[1]), pack2(comb[2], comb[3]),
                                (uint32_t)srcv[q] | ((uint32_t)(dst[q] & (NPB - 1)) << 16),
                                ae8);
            atomicAdd(&bh[dst[q] >> BSH], 1);
        }
    }
    __syncthreads();
    // block-local exclusive scan of bh (391 -> 512-wide Hillis-Steele)
    int hv = (t < NBUCK) ? bh[t] : 0;
    sct[t] = hv;
    __syncthreads();
    #pragma unroll
    for (int off = 1; off < 512; off <<= 1) {
        int xv = (t >= off) ? sct[t - off] : 0;
        __syncthreads();
        sct[t] += xv;
        __syncthreads();
    }
    if (t < NBUCK) {
        bo[t] = sct[t] - hv;                       // local exclusive base
        bg[t] = hv ? atomicAdd(&bcur[t], hv) : 0;  // global run base
        bl[t] = 0;
    }
    __syncthreads();
    if (act) {
        #pragma unroll
        for (int q = 0; q < 4; ++q) {
            int bk = dst[q] >> BSH;
            int off = atomicAdd(&bl[bk], 1);       // fast LDS cursor
            int slot = bo[bk] + off;
            lrec[slot] = (u32x4){rec[q].x, rec[q].y, rec[q].z, rec[q].w};
            gaddr[slot] = bg[bk] + off;
        }
    }
    __syncthreads();
    int total = sct[511];                          // records in this block
    for (int s = t; s < total; s += P1_T) {
        u32x4 r = lrec[s];
        stg[gaddr[s]] = make_uint4(r.x, r.y, r.z, r.w);
    }
}

// fused sort+gather: one 1024-thread block per 128-node bucket (75KB LDS ->
// 2 blocks/CU). phase 0: per-node degrees read from the records' dst byte
// (strided rec.z load; doubles as L2 prefetch for phase 1) + 128-wide scan.
// phase 1: node-sort ~4092 records into LDS. phase 2: per-wave node gather
// from LDS (x-aggregation, W_gat projection after; self-loop mean ae).
__global__ __launch_bounds__(1024) void k_scat2g(const int* __restrict__ bbase,
                                                 const uint4* __restrict__ stg,
                                                 const float* __restrict__ x,
                                                 const float* __restrict__ a_src,
                                                 const float* __restrict__ a_dst,
                                                 const float* __restrict__ W_gat,
                                                 const float* __restrict__ bias_gat,
                                                 float2* __restrict__ h_buf) {
    __shared__ int rp[NPB + 1];
    __shared__ int lcnt[NPB];
    __shared__ int dcnt[NPB];
    __shared__ u32x4 lrec[CAP];      // 74.8KB bucket-local CSR
    int b = blockIdx.x, t = threadIdx.x;
    int n0 = b << BSH;
    int nn = min(NPB, N_NODES - n0);
    int base = bbase[b];
    int total = bbase[b + 1] - base;
    if (t < NPB) dcnt[t] = 0;
    __syncthreads();

    // phase 0: degree count from the records' dst byte (rec.z bits 16..23)
    const uint32_t* stgz = (const uint32_t*)stg;
    for (int e = t; e < total; e += 1024) {
        uint32_t z = stgz[(size_t)(base + e) * 4 + 2];
        atomicAdd(&dcnt[(int)((z >> 16) & 0xFFu)], 1);
    }
    __syncthreads();
    // 128-wide inclusive scan -> exclusive rp[0..128]
    if (t < NPB) rp[t] = dcnt[t];
    __syncthreads();
    #pragma unroll
    for (int off = 1; off < NPB; off <<= 1) {
        int xv = 0;
        if (t < NPB && t >= off) xv = rp[t - off];
        __syncthreads();
        if (t < NPB) rp[t] += xv;
        __syncthreads();
    }
    int incl = (t < NPB) ? rp[t] : 0;
    __syncthreads();
    if (t < NPB) {
        rp[t + 1] = incl;              // rp[1..128] = inclusive prefix
        if (t == 0) rp[0] = 0;
        lcnt[t] = dcnt[t];
    }
    __syncthreads();

    // phase 1: node-sort the stg slice into LDS (coalesced read, L2-hot)
    for (int e = t; e < total; e += 1024) {
        uint4 r = stg[base + e];
        int dl = (int)((r.z >> 16) & 0xFFu);
        int c = atomicSub(&lcnt[dl], 1);
        int slot = rp[dl] + c - 1;
        if (slot < CAP) lrec[slot] = (u32x4){r.x, r.y, r.z, r.w};
    }
    __syncthreads();

    // phase 2: wave wv gathers nodes wv*8 .. wv*8+7 from LDS
    int wv = t >> 6, l = t & 63;
    int h = l & 3;                 // aggregation head
    int slot = l >> 2;             // edge slot 0..15
    int c0 = 2 * l;
    float w00 = W_gat[c0],       w01 = W_gat[c0 + 1];
    float w10 = W_gat[128 + c0], w11 = W_gat[128 + c0 + 1];
    float w20 = W_gat[256 + c0], w21 = W_gat[256 + c0 + 1];
    float2 bia = ((const float2*)bias_gat)[l];

    #pragma unroll 1
    for (int j = 0; j < 8; ++j) {
        int i = wv * 8 + j;
        if (i >= nn) break;                        // wave-uniform
        int n = n0 + i;
        int start = rp[i], end = rp[i + 1];
        int deg = end - start;
        float ad_n = a_dst[n * 4 + h];
        float as_n = a_src[n * 4 + h];
        float sx0 = 0.f, sx1 = 0.f, sx2 = 0.f, den = 0.f, aes = 0.f;

        for (int p0 = start; p0 < end; p0 += 16) {
            int e = p0 + slot;
            float w = 0.f, ae = 0.f;
            int src = n;
            if (e < end) {
                u32x4 rc = lrec[e];
                uint32_t aw = (h < 2) ? rc.x : rc.y;
                float comb = (h & 1) ? bfhi(aw) : bflo(aw);   // ae + a_src[src]
                ae = e4m32f((rc.w >> (h * 8)) & 0xffu);
                src = (int)(rc.z & 0xFFFFu);
                float al = comb + ad_n;
                al = al > 0.f ? al : NEG_SLOPE * al;
                w = __expf(al);
            }
            const float* xr = x + src * 3;                    // L2-hot table
            sx0 += w * xr[0];
            sx1 += w * xr[1];
            sx2 += w * xr[2];
            den += w;
            aes += ae;
        }

        // allreduce across the 16 slots (lanes with equal l&3)
        #pragma unroll
        for (int m = 4; m <= 32; m <<= 1) {
            sx0 += __shfl_xor(sx0, m);
            sx1 += __shfl_xor(sx1, m);
            sx2 += __shfl_xor(sx2, m);
            den += __shfl_xor(den, m);
            aes += __shfl_xor(aes, m);
        }

        // self loop: edge_attr = mean of incoming aeh
        float xn0 = x[n * 3], xn1 = x[n * 3 + 1], xn2 = x[n * 3 + 2];
        float invd = (deg > 0) ? (1.0f / (float)deg) : 1.0f;
        float alS = as_n + ad_n + aes * invd;
        alS = alS > 0.f ? alS : NEG_SLOPE * alS;
        float wS = __expf(alS);
        sx0 += wS * xn0; sx1 += wS * xn1; sx2 += wS * xn2;
        den += wS;

        // lane l needs head l>>4 totals (all lanes hold their head's total)
        int sb = (l >> 4) << 2;
        float t0 = bpermf(sb, sx0);
        float t1 = bpermf(sb, sx1);
        float t2 = bpermf(sb, sx2);
        float td = bpermf(sb, den);

        float r = 1.0f / td;
        float o0 = (t0 * w00 + t1 * w10 + t2 * w20) * r + bia.x;
        float o1 = (t0 * w01 + t1 * w11 + t2 * w21) * r + bia.y;
        o0 = o0 > 0.f ? o0 : (__expf(o0) - 1.0f);   // ELU
        o1 = o1 > 0.f ? o1 : (__expf(o1) - 1.0f);
        h_buf[(size_t)n * 64 + l] = make_float2(o0, o1);
    }
}

// MFMA MLP: 32 rows/block, 4 waves. bf16 hi/lo split (3-term) for ~fp32
// accuracy at matrix-pipe rate. LDS planes [32][136] bf16 (row stride 272B).
__global__ __launch_bounds__(256) void k_mlp(const float* __restrict__ h_buf,
                                             const uint16_t* __restrict__ W1T_hi,
                                             const uint16_t* __restrict__ W1T_lo,
                                             const uint16_t* __restrict__ W2T_hi,
                                             const uint16_t* __restrict__ W2T_lo,
                                             const float* __restrict__ b1,
                                             const float* __restrict__ prelu_a,
                                             const float* __restrict__ b2,
                                             float* __restrict__ out) {
    __shared__ uint16_t hHi[32 * 136];
    __shared__ uint16_t hLo[32 * 136];
    __shared__ uint16_t h1Hi[32 * 136];
    __shared__ uint16_t h1Lo[32 * 136];
    int t = threadIdx.x;
    int nb = blockIdx.x * 32;

    // stage h rows -> bf16 hi/lo planes
    const float4* hb4 = (const float4*)(h_buf + (size_t)nb * 128);
    #pragma unroll
    for (int i = 0; i < 4; ++i) {
        int idx = i * 256 + t;             // float4 index, 1024 total
        int row = idx >> 5, c4 = idx & 31;
        float4 v = make_float4(0.f, 0.f, 0.f, 0.f);
        if (nb + row < N_NODES) v = hb4[idx];
        float xs[4] = {v.x, v.y, v.z, v.w};
        uint32_t hi[4], lo[4];
        #pragma unroll
        for (int j = 0; j < 4; ++j) {
            hi[j] = f2bf(xs[j]);
            lo[j] = f2bf(xs[j] - bflo(hi[j]));
        }
        uint32_t bo = row * 272 + c4 * 8;
        *(uint2*)((char*)hHi + bo) = make_uint2(hi[0] | (hi[1] << 16), hi[2] | (hi[3] << 16));
        *(uint2*)((char*)hLo + bo) = make_uint2(lo[0] | (lo[1] << 16), lo[2] | (lo[3] << 16));
    }
    __syncthreads();

    int w = t >> 6, l = t & 63;
    int lr = l & 15, lg = l >> 4;          // frag row/col lane, k-group
    // ---- layer 1: wave w -> col-tiles {2w, 2w+1}, both row-tiles ----
    float bb0 = b1[(2 * w) * 16 + lr];
    float bb1 = b1[(2 * w + 1) * 16 + lr];
    f32x4 acc[2][2];
    #pragma unroll
    for (int rt = 0; rt < 2; ++rt) {
        acc[rt][0] = (f32x4){bb0, bb0, bb0, bb0};
        acc[rt][1] = (f32x4){bb1, bb1, bb1, bb1};
    }
    #pragma unroll
    for (int s = 0; s < 4; ++s) {
        int koff = s * 64 + lg * 16;       // byte offset of k-chunk
        bf16x8 a_hi[2], a_lo[2], b_hi[2], b_lo[2];
        #pragma unroll
        for (int rt = 0; rt < 2; ++rt) {
            int ro = (rt * 16 + lr) * 272 + koff;
            a_hi[rt] = *(const bf16x8*)((const char*)hHi + ro);
            a_lo[rt] = *(const bf16x8*)((const char*)hLo + ro);
        }
        #pragma unroll
        for (int c = 0; c < 2; ++c) {
            int go = ((2 * w + c) * 16 + lr) * 256 + koff;
            b_hi[c] = *(const bf16x8*)((const char*)W1T_hi + go);
            b_lo[c] = *(const bf16x8*)((const char*)W1T_lo + go);
        }
        #pragma unroll
        for (int rt = 0; rt < 2; ++rt)
            #pragma unroll
            for (int c = 0; c < 2; ++c) {
                acc[rt][c] = __builtin_amdgcn_mfma_f32_16x16x32_bf16(a_hi[rt], b_hi[c], acc[rt][c], 0, 0, 0);
                acc[rt][c] = __builtin_amdgcn_mfma_f32_16x16x32_bf16(a_hi[rt], b_lo[c], acc[rt][c], 0, 0, 0);
                acc[rt][c] = __builtin_amdgcn_mfma_f32_16x16x32_bf16(a_lo[rt], b_hi[c], acc[rt][c], 0, 0, 0);
            }
    }
    // PReLU + re-split -> h1 planes
    float pa = prelu_a[0];
    #pragma unroll
    for (int rt = 0; rt < 2; ++rt)
        #pragma unroll
        for (int c = 0; c < 2; ++c) {
            int n = (2 * w + c) * 16 + lr;
            #pragma unroll
            for (int r = 0; r < 4; ++r) {
                float vv = acc[rt][c][r];
                vv = vv > 0.f ? vv : pa * vv;
                uint32_t hi = f2bf(vv);
                uint32_t lo = f2bf(vv - bflo(hi));
                int m = rt * 16 + lg * 4 + r;
                uint32_t bo = m * 272 + n * 2;
                *(uint16_t*)((char*)h1Hi + bo) = (uint16_t)hi;
                *(uint16_t*)((char*)h1Lo + bo) = (uint16_t)lo;
            }
        }
    __syncthreads();
    // ---- layer 2: wave w -> tile (rt = w&1, ct = w>>1) ----
    int rt2 = w & 1, ct2 = w >> 1;
    float bb2 = b2[ct2 * 16 + lr];
    f32x4 acc2 = (f32x4){bb2, bb2, bb2, bb2};
    #pragma unroll
    for (int s = 0; s < 4; ++s) {
        int koff = s * 64 + lg * 16;
        int ro = (rt2 * 16 + lr) * 272 + koff;
        bf16x8 a_hi = *(const bf16x8*)((const char*)h1Hi + ro);
        bf16x8 a_lo = *(const bf16x8*)((const char*)h1Lo + ro);
        int go = (ct2 * 16 + lr) * 256 + koff;
        bf16x8 w2h = *(const bf16x8*)((const char*)W2T_hi + go);
        bf16x8 w2l = *(const bf16x8*)((const char*)W2T_lo + go);
        acc2 = __builtin_amdgcn_mfma_f32_16x16x32_bf16(a_hi, w2h, acc2, 0, 0, 0);
        acc2 = __builtin_amdgcn_mfma_f32_16x16x32_bf16(a_hi, w2l, acc2, 0, 0, 0);
        acc2 = __builtin_amdgcn_mfma_f32_16x16x32_bf16(a_lo, w2h, acc2, 0, 0, 0);
    }
    #pragma unroll
    for (int r = 0; r < 4; ++r) {
        int m = rt2 * 16 + lg * 4 + r;
        if (nb + m < N_NODES)
            out[(size_t)(nb + m) * 32 + ct2 * 16 + lr] = acc2[r];
    }
}

// ---------------------------------------------------------------- launch

extern "C" void kernel_launch(void* const* d_in, const int* in_sizes, int n_in,
                              void* d_out, int out_size, void* d_ws, size_t ws_size,
                              hipStream_t stream) {
    const float* x        = (const float*)d_in[0];
    const int*   ei       = (const int*)d_in[1];     // int32 per harness contract
    const float* edge_attr= (const float*)d_in[2];
    const float* W_gat    = (const float*)d_in[3];
    const float* att_src  = (const float*)d_in[4];
    const float* att_dst  = (const float*)d_in[5];
    const float* W_edge   = (const float*)d_in[6];
    const float* att_edge = (const float*)d_in[7];
    const float* bias_gat = (const float*)d_in[8];
    const float* W1       = (const float*)d_in[9];
    const float* b1       = (const float*)d_in[10];
    const float* prelu_a  = (const float*)d_in[11];
    const float* W2       = (const float*)d_in[12];
    const float* b2       = (const float*)d_in[13];
    float*       out      = (float*)d_out;

    char* base = (char*)d_ws;
    size_t off = 0;
    auto alloc = [&](size_t bytes) -> void* {
        void* p = base + off;
        off = (off + bytes + 255) & ~(size_t)255;
        return p;
    };
    int*      bcur    = (int*)     alloc((size_t)NBUCK * 4);
    int*      bsum    = (int*)     alloc((size_t)NBUCK * 4);
    int*      bbase   = (int*)     alloc((size_t)(NBUCK + 1) * 4);
    float*    v       = (float*)   alloc(32 * 4);
    uint16_t* W1T_hi  = (uint16_t*)alloc((size_t)128 * 128 * 2);
    uint16_t* W1T_lo  = (uint16_t*)alloc((size_t)128 * 128 * 2);
    uint16_t* W2T_hi  = (uint16_t*)alloc((size_t)32 * 128 * 2);
    uint16_t* W2T_lo  = (uint16_t*)alloc((size_t)32 * 128 * 2);
    float*    a_src   = (float*)   alloc((size_t)N_NODES * 4 * 4);
    float*    a_dst   = (float*)   alloc((size_t)N_NODES * 4 * 4);
    float*    h_buf   = (float*)   alloc((size_t)N_NODES * 128 * 4);
    uint4*    stg     = (uint4*)   alloc((size_t)N_EDGES * 16);

    k_zerob <<<1, 512, 0, stream>>>(bsum);
    k_pre   <<<NB_PRE, 256, 0, stream>>>(x, ei, W_gat, att_src, att_dst,
                                         W_edge, att_edge, W1, W2, bsum,
                                         (float4*)a_src, (float4*)a_dst, v,
                                         W1T_hi, W1T_lo, W2T_hi, W2T_lo);
    k_scanb <<<1, 512, 0, stream>>>(bsum, bbase, bcur);
    k_scat1 <<<P1_BLOCKS, P1_T, 0, stream>>>(
        ei, edge_attr, v, (const float4*)a_src, bcur, stg);
    k_scat2g<<<NBUCK, 1024, 0, stream>>>(
        bbase, stg, x, a_src, a_dst, W_gat, bias_gat, (float2*)h_buf);
    k_mlp   <<<(N_NODES + 31) / 32, 256, 0, stream>>>(
        h_buf, W1T_hi, W1T_lo, W2T_hi, W2T_lo, b1, prelu_a, b2, out);
}